// Round 7
// baseline (217.665 us; speedup 1.0000x reference)
//
#include <hip/hip_runtime.h>
#include <math.h>

#define LLEN 4096
#define CCH 128
#define DI 384
#define NST 4
#define SBN 6        // 3 directions x B=2
#define NB 2
#define FCH 512
#define NCHUNK 128
#define TSTEP 32

typedef short bf16x8 __attribute__((ext_vector_type(8)));
typedef short bf16x4 __attribute__((ext_vector_type(4)));
typedef float f32x4 __attribute__((ext_vector_type(4)));
typedef float f32x8 __attribute__((ext_vector_type(8)));

__device__ __forceinline__ float wave_sum(float v) {
#pragma unroll
    for (int o = 32; o > 0; o >>= 1) v += __shfl_xor(v, o);
    return v;
}

__device__ __forceinline__ short f2bf(float f) {
    unsigned int u = __float_as_uint(f);
    unsigned int r = (u + 0x7fffu + ((u >> 16) & 1u)) >> 16;
    return (short)r;
}
__device__ __forceinline__ float bf2f(short s) {
    return __uint_as_float(((unsigned int)(unsigned short)s) << 16);
}

// ---------------- weight bf16 pool offsets (elements) ----------------
#define OFF_IN  0         // in_w                 768x128
#define OFF_DTC 98304     // composed dt_w@xp_w[:128]  384x384 (rows 0..383)
#define OFF_BC  245760    //   + xp_w rows 128..135 as rows 384..391 (same ld=384)
#define OFF_OUT 248832    // out_w                128x384
#define OFF_FC1 297984    // fc1_w                512x128
#define OFF_FC2 363520    // fc2_w                128x512
#define OFF_END 429056
#define NCONV   281600    // convertible elements (everything except DTC region)
#define NCBLK   1100      // ceil(281600/256)

// merged: plain conversions + dt_w@xp_w composition + colsum zeroing
__global__ __launch_bounds__(256) void conv_comp(const float* __restrict__ in_w,
                                                 const float* __restrict__ xp_w,
                                                 const float* __restrict__ dt_w,
                                                 const float* __restrict__ out_w,
                                                 const float* __restrict__ fc1_w,
                                                 const float* __restrict__ fc2_w,
                                                 short* __restrict__ wb,
                                                 float* __restrict__ colsum)
{
    int bid = blockIdx.x;
    if (bid < NCBLK) {
        int i = bid * 256 + threadIdx.x;
        if (i >= NCONV) return;
        int idx = (i < OFF_DTC) ? i : i + (OFF_OUT - OFF_DTC);  // skip composed region
        float v;
        if (idx < OFF_DTC)      v = in_w[idx];
        else if (idx < OFF_OUT) v = xp_w[128 * 384 + (idx - OFF_BC)];   // bc rows
        else if (idx < OFF_FC1) v = out_w[idx - OFF_OUT];
        else if (idx < OFF_FC2) v = fc1_w[idx - OFF_FC1];
        else                    v = fc2_w[idx - OFF_FC2];
        wb[idx] = f2bf(v);
    } else {
        if (bid == NCBLK) {
            for (int i = threadIdx.x; i < SBN * DI; i += 256) colsum[i] = 0.f;
        }
        int ji = (bid - NCBLK) * 256 + threadIdx.x;   // 0 .. 147455
        int j = ji / 384, k = ji % 384;
        float acc = 0.f;
#pragma unroll 8
        for (int n = 0; n < 128; n++)
            acc += dt_w[j * 128 + n] * xp_w[n * 384 + k];
        wb[OFF_DTC + j * 384 + k] = f2bf(acc);
    }
}

// ---------------- LayerNorm over C=128, FWD rows only (perm invariance), 4 rows/block ----------------
__global__ __launch_bounds__(256) void prep_ln1(const float* __restrict__ x,
                                                const float* __restrict__ g,
                                                const float* __restrict__ b,
                                                short* __restrict__ xn)
{
    int r = blockIdx.x * 4 + (threadIdx.x >> 6);   // 0 .. 8191
    int lane = threadIdx.x & 63;
    const float* src = x + (size_t)r * CCH;
    float v0 = src[lane], v1 = src[lane + 64];
    float m = wave_sum(v0 + v1) * (1.f / 128.f);
    float d0 = v0 - m, d1 = v1 - m;
    float var = wave_sum(d0 * d0 + d1 * d1) * (1.f / 128.f);
    float rstd = rsqrtf(var + 1e-5f);
    short* dst = xn + (size_t)r * CCH;
    dst[lane]      = f2bf(d0 * rstd * g[lane]      + b[lane]);
    dst[lane + 64] = f2bf(d1 * rstd * g[lane + 64] + b[lane + 64]);
}

// ---------------- wide MFMA GEMM (64x128 tile) ----------------
// EPI: 3=bias+residual f32   5=bf16   6=bias bf16
//      7=dtc+bc split: col<384 bias+softplus bf16 -> Cb; col 384..391 f32 -> extra
template<int EPI>
__global__ __launch_bounds__(256) void gemm_w(const short* __restrict__ A, int lda,
                                              const short* __restrict__ W, int ldw, int Ntot,
                                              const float* __restrict__ bias,
                                              const float* __restrict__ res, int ldr,
                                              float* __restrict__ C0,
                                              short* __restrict__ Cb, int ldc,
                                              float* __restrict__ extra,
                                              int Kd)
{
    __shared__ short Als[64 * 72];
    __shared__ short Wls[128 * 72];
    int tid = threadIdx.x;
    int wid = tid >> 6, lane = tid & 63;
    int wm = wid >> 1, wn = wid & 1;
    int l15 = lane & 15, l4 = lane >> 4;
    int bm = blockIdx.x * 64, bn = blockIdx.y * 128;
    int srow = tid >> 3, scol = (tid & 7) * 8;
    f32x4 acc[2][4] = {};
    for (int k0 = 0; k0 < Kd; k0 += 64) {
        bf16x8 av0 = *(const bf16x8*)&A[(size_t)(bm + srow) * lda + k0 + scol];
        bf16x8 av1 = *(const bf16x8*)&A[(size_t)(bm + srow + 32) * lda + k0 + scol];
        bf16x8 wv[4];
#pragma unroll
        for (int q = 0; q < 4; q++) {
            if (EPI == 7) {
                wv[q] = bf16x8{};
                if (bn + srow + 32 * q < Ntot)
                    wv[q] = *(const bf16x8*)&W[(size_t)(bn + srow + 32 * q) * ldw + k0 + scol];
            } else {
                wv[q] = *(const bf16x8*)&W[(size_t)(bn + srow + 32 * q) * ldw + k0 + scol];
            }
        }
        __syncthreads();
        *(bf16x8*)&Als[srow * 72 + scol] = av0;
        *(bf16x8*)&Als[(srow + 32) * 72 + scol] = av1;
#pragma unroll
        for (int q = 0; q < 4; q++)
            *(bf16x8*)&Wls[(srow + 32 * q) * 72 + scol] = wv[q];
        __syncthreads();
#pragma unroll
        for (int ks = 0; ks < 2; ks++) {
            bf16x8 af[2], bw[4];
#pragma unroll
            for (int f = 0; f < 2; f++)
                af[f] = *(const bf16x8*)&Als[(wm * 32 + f * 16 + l15) * 72 + ks * 32 + l4 * 8];
#pragma unroll
            for (int j = 0; j < 4; j++)
                bw[j] = *(const bf16x8*)&Wls[(wn * 64 + j * 16 + l15) * 72 + ks * 32 + l4 * 8];
#pragma unroll
            for (int i = 0; i < 2; i++)
#pragma unroll
                for (int j = 0; j < 4; j++)
                    acc[i][j] = __builtin_amdgcn_mfma_f32_16x16x32_bf16(af[i], bw[j], acc[i][j], 0, 0, 0);
        }
    }
#pragma unroll
    for (int i = 0; i < 2; i++) {
        int row0 = bm + wm * 32 + i * 16 + l4 * 4;
#pragma unroll
        for (int j = 0; j < 4; j++) {
            int col = bn + wn * 64 + j * 16 + l15;
            if (EPI == 7) {
                if (col < 384) {
                    float bv = bias[col];
#pragma unroll
                    for (int r = 0; r < 4; r++) {
                        float v = acc[i][j][r] + bv;
                        v = (v > 20.f) ? v : __logf(1.f + __expf(v));
                        Cb[(size_t)(row0 + r) * ldc + col] = f2bf(v);
                    }
                } else if (col < 392) {
#pragma unroll
                    for (int r = 0; r < 4; r++)
                        extra[(size_t)(row0 + r) * 8 + (col - 384)] = acc[i][j][r];
                }
            } else {
                float bv = (EPI == 3 || EPI == 6) ? bias[col] : 0.f;
#pragma unroll
                for (int r = 0; r < 4; r++) {
                    float v = acc[i][j][r] + bv;
                    if (EPI == 3) v += res[(size_t)(row0 + r) * ldr + col];
                    if (EPI == 5 || EPI == 6)
                        Cb[(size_t)(row0 + r) * ldc + col] = f2bf(v);
                    else
                        C0[(size_t)(row0 + r) * ldc + col] = v;
                }
            }
        }
    }
}

// ---------------- depthwise causal conv K=4 + bias + SiLU over permuted views of hg_fwd ----------------
__global__ __launch_bounds__(192) void dwconv_silu_v3(const short* __restrict__ hg,
                                                      const int* __restrict__ ridx,
                                                      const float* __restrict__ cw,
                                                      const float* __restrict__ cb,
                                                      short* __restrict__ ub)
{
    int t = threadIdx.x;
    int c = t % 48, rs = t / 48;
    int blk = blockIdx.x;            // 768 blocks: 6 sb x 128
    int sb = blk >> 7;
    int s = sb >> 1, bb = sb & 1;
    int l0 = ((blk & 127) << 5) + rs * 8;
    int d0 = c * 8;
    float w0[8], w1[8], w2[8], w3[8], bs[8];
#pragma unroll
    for (int e = 0; e < 8; e++) {
        int d = d0 + e;
        bs[e] = cb[d];
        w0[e] = cw[d * 4 + 0]; w1[e] = cw[d * 4 + 1];
        w2[e] = cw[d * 4 + 2]; w3[e] = cw[d * 4 + 3];
    }
    float r0[8], r1[8], r2[8];
#pragma unroll
    for (int e = 0; e < 8; e++) { r0[e] = 0.f; r1[e] = 0.f; r2[e] = 0.f; }
    if (l0 - 3 >= 0) {
        int j = l0 - 3;
        int sl = (s == 0) ? j : (s == 1 ? LLEN - 1 - j : ridx[j]);
        bf16x8 v = *(const bf16x8*)&hg[(size_t)(bb * LLEN + sl) * 768 + d0];
#pragma unroll
        for (int e = 0; e < 8; e++) r0[e] = bf2f(v[e]);
    }
    if (l0 - 2 >= 0) {
        int j = l0 - 2;
        int sl = (s == 0) ? j : (s == 1 ? LLEN - 1 - j : ridx[j]);
        bf16x8 v = *(const bf16x8*)&hg[(size_t)(bb * LLEN + sl) * 768 + d0];
#pragma unroll
        for (int e = 0; e < 8; e++) r1[e] = bf2f(v[e]);
    }
    if (l0 - 1 >= 0) {
        int j = l0 - 1;
        int sl = (s == 0) ? j : (s == 1 ? LLEN - 1 - j : ridx[j]);
        bf16x8 v = *(const bf16x8*)&hg[(size_t)(bb * LLEN + sl) * 768 + d0];
#pragma unroll
        for (int e = 0; e < 8; e++) r2[e] = bf2f(v[e]);
    }
#pragma unroll
    for (int i = 0; i < 8; i++) {
        int j = l0 + i;
        int sl = (s == 0) ? j : (s == 1 ? LLEN - 1 - j : ridx[j]);
        bf16x8 v = *(const bf16x8*)&hg[(size_t)(bb * LLEN + sl) * 768 + d0];
        float r3[8];
#pragma unroll
        for (int e = 0; e < 8; e++) r3[e] = bf2f(v[e]);
        bf16x8 ov;
#pragma unroll
        for (int e = 0; e < 8; e++) {
            float a = bs[e] + w0[e] * r0[e] + w1[e] * r1[e] + w2[e] * r2[e] + w3[e] * r3[e];
            ov[e] = f2bf(a * __builtin_amdgcn_rcpf(1.f + __expf(-a)));
        }
        *(bf16x8*)&ub[(size_t)(sb * LLEN + j) * DI + d0] = ov;
#pragma unroll
        for (int e = 0; e < 8; e++) { r0[e] = r1[e]; r1[e] = r2[e]; r2[e] = r3[e]; }
    }
}

// ---------------- scan phase A: per-chunk zero-init scan, LDS-staged ----------------
__global__ __launch_bounds__(DI) void scan_phaseA2(const short* __restrict__ dtb,
                                                   const float* __restrict__ bc,
                                                   const short* __restrict__ ub,
                                                   const float* __restrict__ A_log,
                                                   float* __restrict__ PS)
{
    __shared__ short ds_dt[TSTEP * DI];
    __shared__ short ds_u[TSTEP * DI];
    __shared__ float ds_bc[TSTEP * 8];
    int tid = threadIdx.x;
    int bid = blockIdx.x;
    int sb = bid / NCHUNK, chunk = bid % NCHUNK;
    int base = sb * LLEN + chunk * TSTEP;
    {
        int rr = tid / 48, cc = (tid % 48) * 8;
#pragma unroll
        for (int p = 0; p < 4; p++) {
            int row = p * 8 + rr;
            *(bf16x8*)&ds_dt[row * DI + cc] = *(const bf16x8*)&dtb[(size_t)(base + row) * DI + cc];
            *(bf16x8*)&ds_u[row * DI + cc]  = *(const bf16x8*)&ub[(size_t)(base + row) * DI + cc];
        }
        if (tid < TSTEP * 8) ds_bc[tid] = bc[(size_t)base * 8 + tid];
    }
    int d = tid;
    f32x4 al = *(const f32x4*)&A_log[d * 4];
    float a[NST];
#pragma unroll
    for (int n = 0; n < NST; n++) a[n] = -__expf(al[n]);
    __syncthreads();
    float s[NST] = {0.f, 0.f, 0.f, 0.f}, p[NST] = {1.f, 1.f, 1.f, 1.f};
    for (int t = 0; t < TSTEP; t++) {
        float dtv = bf2f(ds_dt[t * DI + d]);
        float dtu = dtv * bf2f(ds_u[t * DI + d]);
#pragma unroll
        for (int n = 0; n < NST; n++) {
            float dA = __expf(dtv * a[n]);
            s[n] = dA * s[n] + dtu * ds_bc[t * 8 + n];
            p[n] *= dA;
        }
    }
    f32x8 v;
#pragma unroll
    for (int n = 0; n < NST; n++) { v[2 * n] = p[n]; v[2 * n + 1] = s[n]; }
    *(f32x8*)&PS[(size_t)(sb * NCHUNK + chunk) * 3072 + d * 8] = v;
}

// ---------------- scan phase B: cross-chunk prefix ----------------
__global__ __launch_bounds__(256) void scan_phaseB2(const float* __restrict__ PS,
                                                    float* __restrict__ I)
{
    int gid = blockIdx.x * 256 + threadIdx.x;
    if (gid >= SBN * 1536) return;
    int sb = gid / 1536, dn = gid % 1536;
    const float* ps = PS + (size_t)sb * NCHUNK * 3072 + dn * 2;
    float* Ip = I + (size_t)sb * NCHUNK * 1536 + dn;
    float st = 0.f;
    for (int c = 0; c < NCHUNK; c += 8) {
        float2 v[8];
#pragma unroll
        for (int q = 0; q < 8; q++) v[q] = *(const float2*)&ps[(size_t)(c + q) * 3072];
#pragma unroll
        for (int q = 0; q < 8; q++) { Ip[(size_t)(c + q) * 1536] = st; st = v[q].x * st + v[q].y; }
    }
}

// ---------------- scan phase C: re-scan + gate + ymix + per-column sums ----------------
__global__ __launch_bounds__(DI) void scan_phaseC3(const short* __restrict__ dtb,
                                                   const float* __restrict__ bc,
                                                   const short* __restrict__ ub,
                                                   const short* __restrict__ hg,
                                                   const int* __restrict__ ridx,
                                                   const float* __restrict__ A_log,
                                                   const float* __restrict__ Dp,
                                                   const float* __restrict__ I,
                                                   short* __restrict__ ymix,
                                                   float* __restrict__ colsum)
{
    __shared__ short ds_dt[TSTEP * DI];
    __shared__ short ds_u[TSTEP * DI];
    __shared__ float ds_bc[TSTEP * 8];
    __shared__ int ds_src[TSTEP];
    int tid = threadIdx.x;
    int bid = blockIdx.x;
    int sb = bid / NCHUNK, chunk = bid % NCHUNK;
    int s2 = sb >> 1, bb = sb & 1;
    int base = sb * LLEN + chunk * TSTEP;
    {
        int rr = tid / 48, cc = (tid % 48) * 8;
#pragma unroll
        for (int p = 0; p < 4; p++) {
            int row = p * 8 + rr;
            *(bf16x8*)&ds_dt[row * DI + cc] = *(const bf16x8*)&dtb[(size_t)(base + row) * DI + cc];
            *(bf16x8*)&ds_u[row * DI + cc]  = *(const bf16x8*)&ub[(size_t)(base + row) * DI + cc];
        }
        if (tid < TSTEP * 8) ds_bc[tid] = bc[(size_t)base * 8 + tid];
        if (tid < TSTEP) {
            int l = chunk * TSTEP + tid;
            int sl = (s2 == 0) ? l : (s2 == 1 ? LLEN - 1 - l : ridx[l]);
            ds_src[tid] = bb * LLEN + sl;
        }
    }
    int d = tid;
    f32x4 al = *(const f32x4*)&A_log[d * 4];
    float a[NST];
#pragma unroll
    for (int n = 0; n < NST; n++) a[n] = -__expf(al[n]);
    __syncthreads();
    float s[NST];
    {
        f32x4 si = *(const f32x4*)&I[(size_t)(sb * NCHUNK + chunk) * 1536 + d * 4];
#pragma unroll
        for (int n = 0; n < NST; n++) s[n] = si[n];
    }
    float Dv = Dp[d];
    float csum = 0.f;
    for (int t = 0; t < TSTEP; t++) {
        float dtv = bf2f(ds_dt[t * DI + d]);
        float uv = bf2f(ds_u[t * DI + d]);
        float dtu = dtv * uv;
        float y = 0.f;
#pragma unroll
        for (int n = 0; n < NST; n++) {
            float dA = __expf(dtv * a[n]);
            s[n] = dA * s[n] + dtu * ds_bc[t * 8 + n];
            y += s[n] * ds_bc[t * 8 + 4 + n];
        }
        float gt = bf2f(hg[(size_t)ds_src[t] * 768 + 384 + d]);
        float sg = gt * __builtin_amdgcn_rcpf(1.f + __expf(-gt));
        float val = (y + uv * Dv) * sg;
        ymix[(size_t)(base + t) * DI + d] = f2bf(val);
        csum += val;
    }
    atomicAdd(&colsum[sb * DI + d], csum);
}

// ---------------- gate: m6 = colsum@out_w^T/4096 -> softmax(g_in@gate_w^T); + inverse perm ----------------
__global__ __launch_bounds__(384) void gate2(const float* __restrict__ colsum,
                                             const float* __restrict__ out_w,
                                             const float* __restrict__ gw,
                                             float* __restrict__ g,
                                             const int* __restrict__ ridx,
                                             int* __restrict__ inv)
{
    if (blockIdx.x == 0) {
        __shared__ float m6[768];
        int tid = threadIdx.x;
        for (int ii = tid; ii < 768; ii += 384) {
            int sb = ii >> 7, c = ii & 127;
            const float* cs = colsum + sb * 384;
            const float* w = out_w + c * 384;
            float acc = 0.f;
#pragma unroll 4
            for (int d = 0; d < 384; d++) acc += cs[d] * w[d];
            m6[ii] = acc * (1.f / 4096.f);
        }
        __syncthreads();
        int lane = tid & 63, p = tid >> 6;
        int bb = p / 3, j2 = p % 3;
        float part = 0.f;
        for (int i = lane; i < 384; i += 64) {
            int j = i >> 7, c = i & 127;
            part += m6[(j * 2 + bb) * 128 + c] * gw[j2 * 384 + i];
        }
        part = wave_sum(part);
        __shared__ float lg[6];
        if (lane == 0) lg[p] = part;
        __syncthreads();
        if (tid < 2) {
            int b2 = tid;
            float a0 = lg[b2 * 3], a1 = lg[b2 * 3 + 1], a2 = lg[b2 * 3 + 2];
            float mx = fmaxf(a0, fmaxf(a1, a2));
            float e0 = __expf(a0 - mx), e1 = __expf(a1 - mx), e2 = __expf(a2 - mx);
            float iv = __builtin_amdgcn_rcpf(e0 + e1 + e2);
            g[b2 * 3] = e0 * iv; g[b2 * 3 + 1] = e1 * iv; g[b2 * 3 + 2] = e2 * iv;
        }
    } else {
        if (threadIdx.x < 256) {
            int l = (blockIdx.x - 1) * 256 + threadIdx.x;
            inv[ridx[l]] = l;
        }
    }
}

// ---------------- fused: direction-combine (in ymix space) + out_proj GEMM + residual + LN2 ----------------
__global__ __launch_bounds__(256) void combine_outproj_ln2(const short* __restrict__ ymix,
                                                           const float* __restrict__ x,
                                                           const float* __restrict__ g,
                                                           const int* __restrict__ inv,
                                                           const short* __restrict__ Wout,
                                                           const float* __restrict__ n2g,
                                                           const float* __restrict__ n2b,
                                                           float* __restrict__ x1,
                                                           short* __restrict__ xn2)
{
    __shared__ short Als[64 * 72];
    __shared__ short Wls[128 * 72];
    __shared__ float xs[64][132];
    __shared__ int ssrc[192];
    __shared__ float msh[64], rsh[64];
    int tid = threadIdx.x;
    int bm = blockIdx.x * 64;          // global row over 8192
    int bb = bm >> 12;
    if (tid < 64) {
        int l = (bm & 4095) + tid;
        ssrc[tid * 3 + 0] = bb * LLEN + l;
        ssrc[tid * 3 + 1] = (2 + bb) * LLEN + (LLEN - 1 - l);
        ssrc[tid * 3 + 2] = (4 + bb) * LLEN + inv[l];
    }
    float g0 = g[bb * 3 + 0], g1 = g[bb * 3 + 1], g2 = g[bb * 3 + 2];
    int wid = tid >> 6, lane = tid & 63;
    int wm = wid >> 1, wn = wid & 1;
    int l15 = lane & 15, l4 = lane >> 4;
    int srow = tid >> 3, scol = (tid & 7) * 8;
    __syncthreads();
    f32x4 acc[2][4] = {};
    for (int k0 = 0; k0 < DI; k0 += 64) {
        bf16x8 cmb[2];
#pragma unroll
        for (int hh = 0; hh < 2; hh++) {
            int r = srow + 32 * hh;
            bf16x8 vf = *(const bf16x8*)&ymix[(size_t)ssrc[r * 3 + 0] * DI + k0 + scol];
            bf16x8 vr = *(const bf16x8*)&ymix[(size_t)ssrc[r * 3 + 1] * DI + k0 + scol];
            bf16x8 vs = *(const bf16x8*)&ymix[(size_t)ssrc[r * 3 + 2] * DI + k0 + scol];
#pragma unroll
            for (int e = 0; e < 8; e++)
                cmb[hh][e] = f2bf(g0 * bf2f(vf[e]) + g1 * bf2f(vr[e]) + g2 * bf2f(vs[e]));
        }
        bf16x8 wv[4];
#pragma unroll
        for (int q = 0; q < 4; q++)
            wv[q] = *(const bf16x8*)&Wout[(size_t)(srow + 32 * q) * DI + k0 + scol];
        __syncthreads();
        *(bf16x8*)&Als[srow * 72 + scol] = cmb[0];
        *(bf16x8*)&Als[(srow + 32) * 72 + scol] = cmb[1];
#pragma unroll
        for (int q = 0; q < 4; q++)
            *(bf16x8*)&Wls[(srow + 32 * q) * 72 + scol] = wv[q];
        __syncthreads();
#pragma unroll
        for (int ks = 0; ks < 2; ks++) {
            bf16x8 af[2], bw[4];
#pragma unroll
            for (int f = 0; f < 2; f++)
                af[f] = *(const bf16x8*)&Als[(wm * 32 + f * 16 + l15) * 72 + ks * 32 + l4 * 8];
#pragma unroll
            for (int j = 0; j < 4; j++)
                bw[j] = *(const bf16x8*)&Wls[(wn * 64 + j * 16 + l15) * 72 + ks * 32 + l4 * 8];
#pragma unroll
            for (int i = 0; i < 2; i++)
#pragma unroll
                for (int j = 0; j < 4; j++)
                    acc[i][j] = __builtin_amdgcn_mfma_f32_16x16x32_bf16(af[i], bw[j], acc[i][j], 0, 0, 0);
        }
    }
    // residual add into LDS
#pragma unroll
    for (int i = 0; i < 2; i++) {
        int rowl = wm * 32 + i * 16 + l4 * 4;
#pragma unroll
        for (int j = 0; j < 4; j++) {
            int col = wn * 64 + j * 16 + l15;
#pragma unroll
            for (int r = 0; r < 4; r++)
                xs[rowl + r][col] = acc[i][j][r] + x[(size_t)(bm + rowl + r) * CCH + col];
        }
    }
    __syncthreads();
    // row LN stats: 4 threads per row
    {
        int row = tid >> 2, q = tid & 3;
        float sum = 0.f, sq = 0.f;
#pragma unroll
        for (int c = q * 32; c < q * 32 + 32; c++) { float v = xs[row][c]; sum += v; sq += v * v; }
        sum += __shfl_xor(sum, 1); sq += __shfl_xor(sq, 1);
        sum += __shfl_xor(sum, 2); sq += __shfl_xor(sq, 2);
        if (q == 0) {
            float m = sum * (1.f / 128.f);
            float var = sq * (1.f / 128.f) - m * m;
            msh[row] = m;
            rsh[row] = rsqrtf(fmaxf(var, 0.f) + 1e-5f);
        }
    }
    __syncthreads();
    {
        int col = tid & 127;
        float gg = n2g[col], b2 = n2b[col];
#pragma unroll
        for (int e = 0; e < 32; e++) {
            int row = e * 2 + (tid >> 7);
            float v = xs[row][col];
            x1[(size_t)(bm + row) * CCH + col] = v;
            xn2[(size_t)(bm + row) * CCH + col] = f2bf((v - msh[row]) * rsh[row] * gg + b2);
        }
    }
}

// ---------------- 3x3 depthwise conv + exact GeLU: sliding-window vectorized ----------------
__global__ __launch_bounds__(256) void peconv_gelu_v2(const short* __restrict__ t,
                                                      const float* __restrict__ pw,
                                                      const float* __restrict__ pb,
                                                      short* __restrict__ t2)
{
    int tid = threadIdx.x;
    int fc = tid & 127;
    int wsr = tid >> 7;
    int blk = blockIdx.x;
    int whalf = blk & 1, h = (blk >> 1) & 63, bb = blk >> 7;
    int w0 = whalf * 32 + wsr * 16;
    int f0 = fc * 4;
    float wt[9][4], bias4[4];
#pragma unroll
    for (int e = 0; e < 4; e++) {
        bias4[e] = pb[f0 + e];
#pragma unroll
        for (int k = 0; k < 9; k++) wt[k][e] = pw[(f0 + e) * 9 + k];
    }
    size_t base = (size_t)bb * 4096 * FCH;
    float cm1[3][4], cc[3][4], cn[3][4];
#pragma unroll
    for (int rr = 0; rr < 3; rr++)
#pragma unroll
        for (int e = 0; e < 4; e++) { cm1[rr][e] = 0.f; cc[rr][e] = 0.f; }
#pragma unroll
    for (int rr = 0; rr < 3; rr++) {
        int hh = h + rr - 1;
        if (hh >= 0 && hh < 64) {
            if (w0 - 1 >= 0) {
                bf16x4 v = *(const bf16x4*)&t[base + ((size_t)hh * 64 + (w0 - 1)) * FCH + f0];
#pragma unroll
                for (int e = 0; e < 4; e++) cm1[rr][e] = bf2f(v[e]);
            }
            bf16x4 v = *(const bf16x4*)&t[base + ((size_t)hh * 64 + w0) * FCH + f0];
#pragma unroll
            for (int e = 0; e < 4; e++) cc[rr][e] = bf2f(v[e]);
        }
    }
#pragma unroll
    for (int i = 0; i < 16; i++) {
        int w = w0 + i;
#pragma unroll
        for (int rr = 0; rr < 3; rr++) {
#pragma unroll
            for (int e = 0; e < 4; e++) cn[rr][e] = 0.f;
            int hh = h + rr - 1;
            if (hh >= 0 && hh < 64 && w + 1 < 64) {
                bf16x4 v = *(const bf16x4*)&t[base + ((size_t)hh * 64 + (w + 1)) * FCH + f0];
#pragma unroll
                for (int e = 0; e < 4; e++) cn[rr][e] = bf2f(v[e]);
            }
        }
        bf16x4 ov;
#pragma unroll
        for (int e = 0; e < 4; e++) {
            float acc = bias4[e];
#pragma unroll
            for (int rr = 0; rr < 3; rr++) {
                acc += wt[rr * 3 + 0][e] * cm1[rr][e];
                acc += wt[rr * 3 + 1][e] * cc[rr][e];
                acc += wt[rr * 3 + 2][e] * cn[rr][e];
            }
            ov[e] = f2bf(0.5f * acc * (1.f + erff(acc * 0.70710678118654752f)));
        }
        *(bf16x4*)&t2[base + ((size_t)h * 64 + w) * FCH + f0] = ov;
#pragma unroll
        for (int rr = 0; rr < 3; rr++)
#pragma unroll
            for (int e = 0; e < 4; e++) { cm1[rr][e] = cc[rr][e]; cc[rr][e] = cn[rr][e]; }
    }
}

extern "C" void kernel_launch(void* const* d_in, const int* in_sizes, int n_in,
                              void* d_out, int out_size, void* d_ws, size_t ws_size,
                              hipStream_t stream)
{
    (void)in_sizes; (void)n_in; (void)ws_size; (void)out_size;
    const float* x      = (const float*)d_in[0];
    const int*   ridx   = (const int*)d_in[1];
    const float* n1g    = (const float*)d_in[4];
    const float* n1b    = (const float*)d_in[5];
    const float* in_w   = (const float*)d_in[6];
    const float* conv_w = (const float*)d_in[7];
    const float* conv_b = (const float*)d_in[8];
    const float* xp_w   = (const float*)d_in[9];
    const float* dt_w   = (const float*)d_in[10];
    const float* dt_b   = (const float*)d_in[11];
    const float* A_log  = (const float*)d_in[12];
    const float* Dp     = (const float*)d_in[13];
    const float* out_w  = (const float*)d_in[14];
    const float* n2g    = (const float*)d_in[15];
    const float* n2b    = (const float*)d_in[16];
    const float* gate_w = (const float*)d_in[17];
    const float* fc1_w  = (const float*)d_in[18];
    const float* fc1_b  = (const float*)d_in[19];
    const float* pe_w   = (const float*)d_in[20];
    const float* pe_b   = (const float*)d_in[21];
    const float* fc2_w  = (const float*)d_in[22];
    const float* fc2_b  = (const float*)d_in[23];
    float* out = (float*)d_out;

    float* ws = (float*)d_ws;
    short* wb   = (short*)ws;                       // [0, 215040)
    float* regA = ws + 215040;                      // xn(bf16) -> I(f32) -> tbuf(bf16)   [2,097,152]
    float* regB = regA + 2097152;                   // hg(bf16, 8192x768) -> {x1,xn2,t2}  [9,437,184]
    float* regC = regB + 9437184;                   // ub(bf16)                           [4,718,592]
    float* regD = regC + 4718592;                   // ymix(bf16)                         [4,718,592]
    float* regE = regD + 4718592;                   // dtb(bf16)                          [4,718,592]
    float* regF = regE + 4718592;                   // PS (f32 pairs)                     [2,359,296]
    float* regG = regF + 2359296;                   // xpbc (f32)                         [196,608]
    float* smallb = regG + 196608;

    short* xn   = (short*)regA;
    float* Ibuf = regA;
    short* tbuf = (short*)regA;
    short* hg   = (short*)regB;                     // 8192*768 bf16
    float* x1   = regB + 3145728;
    short* xn2  = (short*)(regB + 4194304);
    short* t2   = (short*)(regB + 4718592);
    short* ub   = (short*)regC;
    short* ymix = (short*)regD;
    short* dtb  = (short*)regE;
    float* PS   = regF;
    float* xpbc = regG;
    float* colsum = smallb;                         // 6*384 f32
    float* gbuf   = smallb + 2304;
    int*   invb   = (int*)(gbuf + 8);

    const int M6 = SBN * LLEN;   // 24576
    const int M2 = NB * LLEN;    // 8192

    conv_comp<<<NCBLK + 576, 256, 0, stream>>>(in_w, xp_w, dt_w, out_w, fc1_w, fc2_w, wb, colsum);
    // LN1 on fwd rows only (rev/shf are row permutations of fwd through the linear ops)
    prep_ln1<<<M2 / 4, 256, 0, stream>>>(x, n1g, n1b, xn);
    // fused in_proj: [h | gate] N=768, bf16 out, M=8192
    gemm_w<5><<<dim3(M2 / 64, 6), 256, 0, stream>>>(xn, CCH, wb + OFF_IN, CCH, 768, nullptr, nullptr, 0, nullptr, hg, 768, nullptr, CCH);
    // depthwise conv with per-direction row gather
    dwconv_silu_v3<<<768, 192, 0, stream>>>(hg, ridx, conv_w, conv_b, ub);
    // merged dt(softplus, bf16) + B/C(f32) projection: N=392
    gemm_w<7><<<dim3(M6 / 64, 4), 256, 0, stream>>>(ub, DI, wb + OFF_DTC, DI, 392, dt_b, nullptr, 0, nullptr, dtb, DI, xpbc, DI);
    // selective scan (3 kernels; launch boundaries are the grid barriers)
    scan_phaseA2<<<SBN * NCHUNK, DI, 0, stream>>>(dtb, xpbc, ub, A_log, PS);
    scan_phaseB2<<<36, 256, 0, stream>>>(PS, Ibuf);
    scan_phaseC3<<<SBN * NCHUNK, DI, 0, stream>>>(dtb, xpbc, ub, hg, ridx, A_log, Dp, Ibuf, ymix, colsum);
    // gating weights (from ymix colsums, via linearity) + inverse permutation
    gate2<<<17, 384, 0, stream>>>(colsum, out_w, gate_w, gbuf, ridx, invb);
    // fused combine + out_proj + residual + LN2
    combine_outproj_ln2<<<M2 / 64, 256, 0, stream>>>(ymix, x, gbuf, invb, wb + OFF_OUT, n2g, n2b, x1, xn2);
    // MixFFN
    gemm_w<6><<<dim3(M2 / 64, 4), 256, 0, stream>>>(xn2, CCH, wb + OFF_FC1, CCH, FCH, fc1_b, nullptr, 0, nullptr, tbuf, FCH, nullptr, CCH);
    peconv_gelu_v2<<<256, 256, 0, stream>>>(tbuf, pe_w, pe_b, t2);
    gemm_w<3><<<dim3(M2 / 64, 1), 256, 0, stream>>>(t2, FCH, wb + OFF_FC2, FCH, CCH, fc2_b, x1, CCH, out, nullptr, CCH, nullptr, FCH);
}

// Round 8
// 180.569 us; speedup vs baseline: 1.2054x; 1.2054x over previous
//
#include <hip/hip_runtime.h>
#include <math.h>

#define LLEN 4096
#define CCH 128
#define DI 384
#define NST 4
#define SBN 6        // 3 directions x B=2
#define NB 2
#define FCH 512
#define NCHUNK 128
#define TSTEP 32

typedef short bf16x8 __attribute__((ext_vector_type(8)));
typedef short bf16x4 __attribute__((ext_vector_type(4)));
typedef float f32x4 __attribute__((ext_vector_type(4)));
typedef float f32x8 __attribute__((ext_vector_type(8)));

__device__ __forceinline__ float wave_sum(float v) {
#pragma unroll
    for (int o = 32; o > 0; o >>= 1) v += __shfl_xor(v, o);
    return v;
}

__device__ __forceinline__ short f2bf(float f) {
    unsigned int u = __float_as_uint(f);
    unsigned int r = (u + 0x7fffu + ((u >> 16) & 1u)) >> 16;
    return (short)r;
}
__device__ __forceinline__ float bf2f(short s) {
    return __uint_as_float(((unsigned int)(unsigned short)s) << 16);
}

// ---------------- weight bf16 pool offsets (elements) ----------------
#define OFF_IN  0         // in_w                 768x128
#define OFF_DTC 98304     // composed dt_w@xp_w[:128]  384x384 (rows 0..383)
#define OFF_BC  245760    //   + xp_w rows 128..135 as rows 384..391 (same ld=384)
#define OFF_OUT 248832    // out_w                128x384
#define OFF_FC1 297984    // fc1_w                512x128
#define OFF_FC2 363520    // fc2_w                128x512
#define OFF_END 429056
#define NCONV   281600    // convertible elements (everything except DTC region)
#define NCBLK   1100      // ceil(281600/256)
#define GWCBLK  14        // ceil(3456/256)

// merged: conversions + dt_w@xp_w composition + gwc precompute + inverse perm + colsum zero
__global__ __launch_bounds__(256) void conv_comp(const float* __restrict__ in_w,
                                                 const float* __restrict__ xp_w,
                                                 const float* __restrict__ dt_w,
                                                 const float* __restrict__ out_w,
                                                 const float* __restrict__ fc1_w,
                                                 const float* __restrict__ fc2_w,
                                                 const float* __restrict__ gate_w,
                                                 const int* __restrict__ ridx,
                                                 short* __restrict__ wb,
                                                 float* __restrict__ colsum,
                                                 float* __restrict__ gwc,
                                                 int* __restrict__ inv)
{
    int bid = blockIdx.x;
    if (bid < NCBLK) {
        int i = bid * 256 + threadIdx.x;
        if (i >= NCONV) return;
        int idx = (i < OFF_DTC) ? i : i + (OFF_OUT - OFF_DTC);  // skip composed region
        float v;
        if (idx < OFF_DTC)      v = in_w[idx];
        else if (idx < OFF_OUT) v = xp_w[128 * 384 + (idx - OFF_BC)];   // bc rows
        else if (idx < OFF_FC1) v = out_w[idx - OFF_OUT];
        else if (idx < OFF_FC2) v = fc1_w[idx - OFF_FC1];
        else                    v = fc2_w[idx - OFF_FC2];
        wb[idx] = f2bf(v);
    } else if (bid < NCBLK + 576) {
        if (bid == NCBLK) {
            for (int i = threadIdx.x; i < SBN * DI; i += 256) colsum[i] = 0.f;
        }
        int ji = (bid - NCBLK) * 256 + threadIdx.x;   // 0 .. 147455
        int j = ji / 384, k = ji % 384;
        float acc = 0.f;
#pragma unroll 8
        for (int n = 0; n < 128; n++)
            acc += dt_w[j * 128 + n] * xp_w[n * 384 + k];
        wb[OFF_DTC + j * 384 + k] = f2bf(acc);
    } else if (bid < NCBLK + 576 + GWCBLK) {
        // gwc[j][s][d] = sum_c gate_w[j, s*128+c] * out_w[c, d]
        int idx = (bid - NCBLK - 576) * 256 + threadIdx.x;
        if (idx >= 3456) return;
        int j = idx / 1152, rem = idx % 1152;
        int s = rem / 384, d = rem % 384;
        float acc = 0.f;
#pragma unroll 8
        for (int c = 0; c < 128; c++)
            acc += gate_w[j * 384 + s * 128 + c] * out_w[c * 384 + d];
        gwc[idx] = acc;
    } else {
        int l = (bid - NCBLK - 576 - GWCBLK) * 256 + threadIdx.x;
        if (l < LLEN) inv[ridx[l]] = l;
    }
}

// ---------------- LayerNorm over C=128, FWD rows only (perm invariance), 4 rows/block ----------------
__global__ __launch_bounds__(256) void prep_ln1(const float* __restrict__ x,
                                                const float* __restrict__ g,
                                                const float* __restrict__ b,
                                                short* __restrict__ xn)
{
    int r = blockIdx.x * 4 + (threadIdx.x >> 6);   // 0 .. 8191
    int lane = threadIdx.x & 63;
    const float* src = x + (size_t)r * CCH;
    float v0 = src[lane], v1 = src[lane + 64];
    float m = wave_sum(v0 + v1) * (1.f / 128.f);
    float d0 = v0 - m, d1 = v1 - m;
    float var = wave_sum(d0 * d0 + d1 * d1) * (1.f / 128.f);
    float rstd = rsqrtf(var + 1e-5f);
    short* dst = xn + (size_t)r * CCH;
    dst[lane]      = f2bf(d0 * rstd * g[lane]      + b[lane]);
    dst[lane + 64] = f2bf(d1 * rstd * g[lane + 64] + b[lane + 64]);
}

// ---------------- wide MFMA GEMM (64x128 tile) ----------------
// EPI: 3=bias+residual f32   5=bf16   6=bias bf16
//      7=dtc+bc split: col<384 bias+softplus bf16 -> Cb; col 384..391 f32 -> extra
template<int EPI>
__global__ __launch_bounds__(256) void gemm_w(const short* __restrict__ A, int lda,
                                              const short* __restrict__ W, int ldw, int Ntot,
                                              const float* __restrict__ bias,
                                              const float* __restrict__ res, int ldr,
                                              float* __restrict__ C0,
                                              short* __restrict__ Cb, int ldc,
                                              float* __restrict__ extra,
                                              int Kd)
{
    __shared__ short Als[64 * 72];
    __shared__ short Wls[128 * 72];
    int tid = threadIdx.x;
    int wid = tid >> 6, lane = tid & 63;
    int wm = wid >> 1, wn = wid & 1;
    int l15 = lane & 15, l4 = lane >> 4;
    int bm = blockIdx.x * 64, bn = blockIdx.y * 128;
    int srow = tid >> 3, scol = (tid & 7) * 8;
    f32x4 acc[2][4] = {};
    for (int k0 = 0; k0 < Kd; k0 += 64) {
        bf16x8 av0 = *(const bf16x8*)&A[(size_t)(bm + srow) * lda + k0 + scol];
        bf16x8 av1 = *(const bf16x8*)&A[(size_t)(bm + srow + 32) * lda + k0 + scol];
        bf16x8 wv[4];
#pragma unroll
        for (int q = 0; q < 4; q++) {
            if (EPI == 7) {
                wv[q] = bf16x8{};
                if (bn + srow + 32 * q < Ntot)
                    wv[q] = *(const bf16x8*)&W[(size_t)(bn + srow + 32 * q) * ldw + k0 + scol];
            } else {
                wv[q] = *(const bf16x8*)&W[(size_t)(bn + srow + 32 * q) * ldw + k0 + scol];
            }
        }
        __syncthreads();
        *(bf16x8*)&Als[srow * 72 + scol] = av0;
        *(bf16x8*)&Als[(srow + 32) * 72 + scol] = av1;
#pragma unroll
        for (int q = 0; q < 4; q++)
            *(bf16x8*)&Wls[(srow + 32 * q) * 72 + scol] = wv[q];
        __syncthreads();
#pragma unroll
        for (int ks = 0; ks < 2; ks++) {
            bf16x8 af[2], bw[4];
#pragma unroll
            for (int f = 0; f < 2; f++)
                af[f] = *(const bf16x8*)&Als[(wm * 32 + f * 16 + l15) * 72 + ks * 32 + l4 * 8];
#pragma unroll
            for (int j = 0; j < 4; j++)
                bw[j] = *(const bf16x8*)&Wls[(wn * 64 + j * 16 + l15) * 72 + ks * 32 + l4 * 8];
#pragma unroll
            for (int i = 0; i < 2; i++)
#pragma unroll
                for (int j = 0; j < 4; j++)
                    acc[i][j] = __builtin_amdgcn_mfma_f32_16x16x32_bf16(af[i], bw[j], acc[i][j], 0, 0, 0);
        }
    }
#pragma unroll
    for (int i = 0; i < 2; i++) {
        int row0 = bm + wm * 32 + i * 16 + l4 * 4;
#pragma unroll
        for (int j = 0; j < 4; j++) {
            int col = bn + wn * 64 + j * 16 + l15;
            if (EPI == 7) {
                if (col < 384) {
                    float bv = bias[col];
#pragma unroll
                    for (int r = 0; r < 4; r++) {
                        float v = acc[i][j][r] + bv;
                        v = (v > 20.f) ? v : __logf(1.f + __expf(v));
                        Cb[(size_t)(row0 + r) * ldc + col] = f2bf(v);
                    }
                } else if (col < 392) {
#pragma unroll
                    for (int r = 0; r < 4; r++)
                        extra[(size_t)(row0 + r) * 8 + (col - 384)] = acc[i][j][r];
                }
            } else {
                float bv = (EPI == 3 || EPI == 6) ? bias[col] : 0.f;
#pragma unroll
                for (int r = 0; r < 4; r++) {
                    float v = acc[i][j][r] + bv;
                    if (EPI == 3) v += res[(size_t)(row0 + r) * ldr + col];
                    if (EPI == 5 || EPI == 6)
                        Cb[(size_t)(row0 + r) * ldc + col] = f2bf(v);
                    else
                        C0[(size_t)(row0 + r) * ldc + col] = v;
                }
            }
        }
    }
}

// ---------------- depthwise causal conv K=4 + bias + SiLU over permuted views of hg_fwd ----------------
__global__ __launch_bounds__(192) void dwconv_silu_v3(const short* __restrict__ hg,
                                                      const int* __restrict__ ridx,
                                                      const float* __restrict__ cw,
                                                      const float* __restrict__ cb,
                                                      short* __restrict__ ub)
{
    int t = threadIdx.x;
    int c = t % 48, rs = t / 48;
    int blk = blockIdx.x;            // 768 blocks: 6 sb x 128
    int sb = blk >> 7;
    int s = sb >> 1, bb = sb & 1;
    int l0 = ((blk & 127) << 5) + rs * 8;
    int d0 = c * 8;
    float w0[8], w1[8], w2[8], w3[8], bs[8];
#pragma unroll
    for (int e = 0; e < 8; e++) {
        int d = d0 + e;
        bs[e] = cb[d];
        w0[e] = cw[d * 4 + 0]; w1[e] = cw[d * 4 + 1];
        w2[e] = cw[d * 4 + 2]; w3[e] = cw[d * 4 + 3];
    }
    float r0[8], r1[8], r2[8];
#pragma unroll
    for (int e = 0; e < 8; e++) { r0[e] = 0.f; r1[e] = 0.f; r2[e] = 0.f; }
    if (l0 - 3 >= 0) {
        int j = l0 - 3;
        int sl = (s == 0) ? j : (s == 1 ? LLEN - 1 - j : ridx[j]);
        bf16x8 v = *(const bf16x8*)&hg[(size_t)(bb * LLEN + sl) * 768 + d0];
#pragma unroll
        for (int e = 0; e < 8; e++) r0[e] = bf2f(v[e]);
    }
    if (l0 - 2 >= 0) {
        int j = l0 - 2;
        int sl = (s == 0) ? j : (s == 1 ? LLEN - 1 - j : ridx[j]);
        bf16x8 v = *(const bf16x8*)&hg[(size_t)(bb * LLEN + sl) * 768 + d0];
#pragma unroll
        for (int e = 0; e < 8; e++) r1[e] = bf2f(v[e]);
    }
    if (l0 - 1 >= 0) {
        int j = l0 - 1;
        int sl = (s == 0) ? j : (s == 1 ? LLEN - 1 - j : ridx[j]);
        bf16x8 v = *(const bf16x8*)&hg[(size_t)(bb * LLEN + sl) * 768 + d0];
#pragma unroll
        for (int e = 0; e < 8; e++) r2[e] = bf2f(v[e]);
    }
#pragma unroll
    for (int i = 0; i < 8; i++) {
        int j = l0 + i;
        int sl = (s == 0) ? j : (s == 1 ? LLEN - 1 - j : ridx[j]);
        bf16x8 v = *(const bf16x8*)&hg[(size_t)(bb * LLEN + sl) * 768 + d0];
        float r3[8];
#pragma unroll
        for (int e = 0; e < 8; e++) r3[e] = bf2f(v[e]);
        bf16x8 ov;
#pragma unroll
        for (int e = 0; e < 8; e++) {
            float a = bs[e] + w0[e] * r0[e] + w1[e] * r1[e] + w2[e] * r2[e] + w3[e] * r3[e];
            ov[e] = f2bf(a * __builtin_amdgcn_rcpf(1.f + __expf(-a)));
        }
        *(bf16x8*)&ub[(size_t)(sb * LLEN + j) * DI + d0] = ov;
#pragma unroll
        for (int e = 0; e < 8; e++) { r0[e] = r1[e]; r1[e] = r2[e]; r2[e] = r3[e]; }
    }
}

// ---------------- scan phase A: per-chunk zero-init scan, LDS-staged ----------------
__global__ __launch_bounds__(DI) void scan_phaseA2(const short* __restrict__ dtb,
                                                   const float* __restrict__ bc,
                                                   const short* __restrict__ ub,
                                                   const float* __restrict__ A_log,
                                                   float* __restrict__ PS)
{
    __shared__ short ds_dt[TSTEP * DI];
    __shared__ short ds_u[TSTEP * DI];
    __shared__ float ds_bc[TSTEP * 8];
    int tid = threadIdx.x;
    int bid = blockIdx.x;
    int sb = bid / NCHUNK, chunk = bid % NCHUNK;
    int base = sb * LLEN + chunk * TSTEP;
    {
        int rr = tid / 48, cc = (tid % 48) * 8;
#pragma unroll
        for (int p = 0; p < 4; p++) {
            int row = p * 8 + rr;
            *(bf16x8*)&ds_dt[row * DI + cc] = *(const bf16x8*)&dtb[(size_t)(base + row) * DI + cc];
            *(bf16x8*)&ds_u[row * DI + cc]  = *(const bf16x8*)&ub[(size_t)(base + row) * DI + cc];
        }
        if (tid < TSTEP * 8) ds_bc[tid] = bc[(size_t)base * 8 + tid];
    }
    int d = tid;
    f32x4 al = *(const f32x4*)&A_log[d * 4];
    float a[NST];
#pragma unroll
    for (int n = 0; n < NST; n++) a[n] = -__expf(al[n]);
    __syncthreads();
    float s[NST] = {0.f, 0.f, 0.f, 0.f}, p[NST] = {1.f, 1.f, 1.f, 1.f};
    for (int t = 0; t < TSTEP; t++) {
        float dtv = bf2f(ds_dt[t * DI + d]);
        float dtu = dtv * bf2f(ds_u[t * DI + d]);
#pragma unroll
        for (int n = 0; n < NST; n++) {
            float dA = __expf(dtv * a[n]);
            s[n] = dA * s[n] + dtu * ds_bc[t * 8 + n];
            p[n] *= dA;
        }
    }
    f32x8 v;
#pragma unroll
    for (int n = 0; n < NST; n++) { v[2 * n] = p[n]; v[2 * n + 1] = s[n]; }
    *(f32x8*)&PS[(size_t)(sb * NCHUNK + chunk) * 3072 + d * 8] = v;
}

// ---------------- scan phase B: cross-chunk prefix ----------------
__global__ __launch_bounds__(256) void scan_phaseB2(const float* __restrict__ PS,
                                                    float* __restrict__ I)
{
    int gid = blockIdx.x * 256 + threadIdx.x;
    if (gid >= SBN * 1536) return;
    int sb = gid / 1536, dn = gid % 1536;
    const float* ps = PS + (size_t)sb * NCHUNK * 3072 + dn * 2;
    float* Ip = I + (size_t)sb * NCHUNK * 1536 + dn;
    float st = 0.f;
    for (int c = 0; c < NCHUNK; c += 8) {
        float2 v[8];
#pragma unroll
        for (int q = 0; q < 8; q++) v[q] = *(const float2*)&ps[(size_t)(c + q) * 3072];
#pragma unroll
        for (int q = 0; q < 8; q++) { Ip[(size_t)(c + q) * 1536] = st; st = v[q].x * st + v[q].y; }
    }
}

// ---------------- scan phase C: re-scan + gate + ymix + per-column sums ----------------
__global__ __launch_bounds__(DI) void scan_phaseC3(const short* __restrict__ dtb,
                                                   const float* __restrict__ bc,
                                                   const short* __restrict__ ub,
                                                   const short* __restrict__ hg,
                                                   const int* __restrict__ ridx,
                                                   const float* __restrict__ A_log,
                                                   const float* __restrict__ Dp,
                                                   const float* __restrict__ I,
                                                   short* __restrict__ ymix,
                                                   float* __restrict__ colsum)
{
    __shared__ short ds_dt[TSTEP * DI];
    __shared__ short ds_u[TSTEP * DI];
    __shared__ float ds_bc[TSTEP * 8];
    __shared__ int ds_src[TSTEP];
    int tid = threadIdx.x;
    int bid = blockIdx.x;
    int sb = bid / NCHUNK, chunk = bid % NCHUNK;
    int s2 = sb >> 1, bb = sb & 1;
    int base = sb * LLEN + chunk * TSTEP;
    {
        int rr = tid / 48, cc = (tid % 48) * 8;
#pragma unroll
        for (int p = 0; p < 4; p++) {
            int row = p * 8 + rr;
            *(bf16x8*)&ds_dt[row * DI + cc] = *(const bf16x8*)&dtb[(size_t)(base + row) * DI + cc];
            *(bf16x8*)&ds_u[row * DI + cc]  = *(const bf16x8*)&ub[(size_t)(base + row) * DI + cc];
        }
        if (tid < TSTEP * 8) ds_bc[tid] = bc[(size_t)base * 8 + tid];
        if (tid < TSTEP) {
            int l = chunk * TSTEP + tid;
            int sl = (s2 == 0) ? l : (s2 == 1 ? LLEN - 1 - l : ridx[l]);
            ds_src[tid] = bb * LLEN + sl;
        }
    }
    int d = tid;
    f32x4 al = *(const f32x4*)&A_log[d * 4];
    float a[NST];
#pragma unroll
    for (int n = 0; n < NST; n++) a[n] = -__expf(al[n]);
    __syncthreads();
    float s[NST];
    {
        f32x4 si = *(const f32x4*)&I[(size_t)(sb * NCHUNK + chunk) * 1536 + d * 4];
#pragma unroll
        for (int n = 0; n < NST; n++) s[n] = si[n];
    }
    float Dv = Dp[d];
    float csum = 0.f;
    for (int t = 0; t < TSTEP; t++) {
        float dtv = bf2f(ds_dt[t * DI + d]);
        float uv = bf2f(ds_u[t * DI + d]);
        float dtu = dtv * uv;
        float y = 0.f;
#pragma unroll
        for (int n = 0; n < NST; n++) {
            float dA = __expf(dtv * a[n]);
            s[n] = dA * s[n] + dtu * ds_bc[t * 8 + n];
            y += s[n] * ds_bc[t * 8 + 4 + n];
        }
        float gt = bf2f(hg[(size_t)ds_src[t] * 768 + 384 + d]);
        float sg = gt * __builtin_amdgcn_rcpf(1.f + __expf(-gt));
        float val = (y + uv * Dv) * sg;
        ymix[(size_t)(base + t) * DI + d] = f2bf(val);
        csum += val;
    }
    atomicAdd(&colsum[sb * DI + d], csum);
}

// ---------------- gate: logits via precomputed gwc; softmax ----------------
__global__ __launch_bounds__(384) void gate3(const float* __restrict__ colsum,
                                             const float* __restrict__ gwc,
                                             float* __restrict__ g)
{
    int tid = threadIdx.x;
    int lane = tid & 63, p = tid >> 6;     // p = bb*3 + j
    int bb = p / 3, j = p % 3;
    float part = 0.f;
    for (int i = lane; i < 1152; i += 64) {
        int s = i / 384, d = i % 384;
        part += colsum[(s * 2 + bb) * 384 + d] * gwc[j * 1152 + i];
    }
    part = wave_sum(part) * (1.f / 4096.f);
    __shared__ float lg[6];
    if (lane == 0) lg[p] = part;
    __syncthreads();
    if (tid < 2) {
        int b2 = tid;
        float a0 = lg[b2 * 3], a1 = lg[b2 * 3 + 1], a2 = lg[b2 * 3 + 2];
        float mx = fmaxf(a0, fmaxf(a1, a2));
        float e0 = __expf(a0 - mx), e1 = __expf(a1 - mx), e2 = __expf(a2 - mx);
        float iv = __builtin_amdgcn_rcpf(e0 + e1 + e2);
        g[b2 * 3] = e0 * iv; g[b2 * 3 + 1] = e1 * iv; g[b2 * 3 + 2] = e2 * iv;
    }
}

// ---------------- fused: direction-combine (in ymix space) + out_proj GEMM + residual + LN2 ----------------
__global__ __launch_bounds__(256) void combine_outproj_ln2(const short* __restrict__ ymix,
                                                           const float* __restrict__ x,
                                                           const float* __restrict__ g,
                                                           const int* __restrict__ inv,
                                                           const short* __restrict__ Wout,
                                                           const float* __restrict__ n2g,
                                                           const float* __restrict__ n2b,
                                                           float* __restrict__ x1,
                                                           short* __restrict__ xn2)
{
    __shared__ short Als[64 * 72];
    __shared__ short Wls[128 * 72];
    __shared__ float xs[64][132];
    __shared__ int ssrc[192];
    __shared__ float msh[64], rsh[64];
    int tid = threadIdx.x;
    int bm = blockIdx.x * 64;          // global row over 8192
    int bb = bm >> 12;
    if (tid < 64) {
        int l = (bm & 4095) + tid;
        ssrc[tid * 3 + 0] = bb * LLEN + l;
        ssrc[tid * 3 + 1] = (2 + bb) * LLEN + (LLEN - 1 - l);
        ssrc[tid * 3 + 2] = (4 + bb) * LLEN + inv[l];
    }
    float g0 = g[bb * 3 + 0], g1 = g[bb * 3 + 1], g2 = g[bb * 3 + 2];
    int wid = tid >> 6, lane = tid & 63;
    int wm = wid >> 1, wn = wid & 1;
    int l15 = lane & 15, l4 = lane >> 4;
    int srow = tid >> 3, scol = (tid & 7) * 8;
    __syncthreads();
    f32x4 acc[2][4] = {};
    for (int k0 = 0; k0 < DI; k0 += 64) {
        bf16x8 cmb[2];
#pragma unroll
        for (int hh = 0; hh < 2; hh++) {
            int r = srow + 32 * hh;
            bf16x8 vf = *(const bf16x8*)&ymix[(size_t)ssrc[r * 3 + 0] * DI + k0 + scol];
            bf16x8 vr = *(const bf16x8*)&ymix[(size_t)ssrc[r * 3 + 1] * DI + k0 + scol];
            bf16x8 vs = *(const bf16x8*)&ymix[(size_t)ssrc[r * 3 + 2] * DI + k0 + scol];
#pragma unroll
            for (int e = 0; e < 8; e++)
                cmb[hh][e] = f2bf(g0 * bf2f(vf[e]) + g1 * bf2f(vr[e]) + g2 * bf2f(vs[e]));
        }
        bf16x8 wv[4];
#pragma unroll
        for (int q = 0; q < 4; q++)
            wv[q] = *(const bf16x8*)&Wout[(size_t)(srow + 32 * q) * DI + k0 + scol];
        __syncthreads();
        *(bf16x8*)&Als[srow * 72 + scol] = cmb[0];
        *(bf16x8*)&Als[(srow + 32) * 72 + scol] = cmb[1];
#pragma unroll
        for (int q = 0; q < 4; q++)
            *(bf16x8*)&Wls[(srow + 32 * q) * 72 + scol] = wv[q];
        __syncthreads();
#pragma unroll
        for (int ks = 0; ks < 2; ks++) {
            bf16x8 af[2], bw[4];
#pragma unroll
            for (int f = 0; f < 2; f++)
                af[f] = *(const bf16x8*)&Als[(wm * 32 + f * 16 + l15) * 72 + ks * 32 + l4 * 8];
#pragma unroll
            for (int j = 0; j < 4; j++)
                bw[j] = *(const bf16x8*)&Wls[(wn * 64 + j * 16 + l15) * 72 + ks * 32 + l4 * 8];
#pragma unroll
            for (int i = 0; i < 2; i++)
#pragma unroll
                for (int j = 0; j < 4; j++)
                    acc[i][j] = __builtin_amdgcn_mfma_f32_16x16x32_bf16(af[i], bw[j], acc[i][j], 0, 0, 0);
        }
    }
    // residual add into LDS
#pragma unroll
    for (int i = 0; i < 2; i++) {
        int rowl = wm * 32 + i * 16 + l4 * 4;
#pragma unroll
        for (int j = 0; j < 4; j++) {
            int col = wn * 64 + j * 16 + l15;
#pragma unroll
            for (int r = 0; r < 4; r++)
                xs[rowl + r][col] = acc[i][j][r] + x[(size_t)(bm + rowl + r) * CCH + col];
        }
    }
    __syncthreads();
    // row LN stats: 4 threads per row
    {
        int row = tid >> 2, q = tid & 3;
        float sum = 0.f, sq = 0.f;
#pragma unroll
        for (int c = q * 32; c < q * 32 + 32; c++) { float v = xs[row][c]; sum += v; sq += v * v; }
        sum += __shfl_xor(sum, 1); sq += __shfl_xor(sq, 1);
        sum += __shfl_xor(sum, 2); sq += __shfl_xor(sq, 2);
        if (q == 0) {
            float m = sum * (1.f / 128.f);
            float var = sq * (1.f / 128.f) - m * m;
            msh[row] = m;
            rsh[row] = rsqrtf(fmaxf(var, 0.f) + 1e-5f);
        }
    }
    __syncthreads();
    {
        int col = tid & 127;
        float gg = n2g[col], b2 = n2b[col];
#pragma unroll
        for (int e = 0; e < 32; e++) {
            int row = e * 2 + (tid >> 7);
            float v = xs[row][col];
            x1[(size_t)(bm + row) * CCH + col] = v;
            xn2[(size_t)(bm + row) * CCH + col] = f2bf((v - msh[row]) * rsh[row] * gg + b2);
        }
    }
}

// ---------------- 3x3 depthwise conv + exact GeLU: sliding-window vectorized ----------------
__global__ __launch_bounds__(256) void peconv_gelu_v2(const short* __restrict__ t,
                                                      const float* __restrict__ pw,
                                                      const float* __restrict__ pb,
                                                      short* __restrict__ t2)
{
    int tid = threadIdx.x;
    int fc = tid & 127;
    int wsr = tid >> 7;
    int blk = blockIdx.x;
    int whalf = blk & 1, h = (blk >> 1) & 63, bb = blk >> 7;
    int w0 = whalf * 32 + wsr * 16;
    int f0 = fc * 4;
    float wt[9][4], bias4[4];
#pragma unroll
    for (int e = 0; e < 4; e++) {
        bias4[e] = pb[f0 + e];
#pragma unroll
        for (int k = 0; k < 9; k++) wt[k][e] = pw[(f0 + e) * 9 + k];
    }
    size_t base = (size_t)bb * 4096 * FCH;
    float cm1[3][4], cc[3][4], cn[3][4];
#pragma unroll
    for (int rr = 0; rr < 3; rr++)
#pragma unroll
        for (int e = 0; e < 4; e++) { cm1[rr][e] = 0.f; cc[rr][e] = 0.f; }
#pragma unroll
    for (int rr = 0; rr < 3; rr++) {
        int hh = h + rr - 1;
        if (hh >= 0 && hh < 64) {
            if (w0 - 1 >= 0) {
                bf16x4 v = *(const bf16x4*)&t[base + ((size_t)hh * 64 + (w0 - 1)) * FCH + f0];
#pragma unroll
                for (int e = 0; e < 4; e++) cm1[rr][e] = bf2f(v[e]);
            }
            bf16x4 v = *(const bf16x4*)&t[base + ((size_t)hh * 64 + w0) * FCH + f0];
#pragma unroll
            for (int e = 0; e < 4; e++) cc[rr][e] = bf2f(v[e]);
        }
    }
#pragma unroll
    for (int i = 0; i < 16; i++) {
        int w = w0 + i;
#pragma unroll
        for (int rr = 0; rr < 3; rr++) {
#pragma unroll
            for (int e = 0; e < 4; e++) cn[rr][e] = 0.f;
            int hh = h + rr - 1;
            if (hh >= 0 && hh < 64 && w + 1 < 64) {
                bf16x4 v = *(const bf16x4*)&t[base + ((size_t)hh * 64 + (w + 1)) * FCH + f0];
#pragma unroll
                for (int e = 0; e < 4; e++) cn[rr][e] = bf2f(v[e]);
            }
        }
        bf16x4 ov;
#pragma unroll
        for (int e = 0; e < 4; e++) {
            float acc = bias4[e];
#pragma unroll
            for (int rr = 0; rr < 3; rr++) {
                acc += wt[rr * 3 + 0][e] * cm1[rr][e];
                acc += wt[rr * 3 + 1][e] * cc[rr][e];
                acc += wt[rr * 3 + 2][e] * cn[rr][e];
            }
            ov[e] = f2bf(0.5f * acc * (1.f + erff(acc * 0.70710678118654752f)));
        }
        *(bf16x4*)&t2[base + ((size_t)h * 64 + w) * FCH + f0] = ov;
#pragma unroll
        for (int rr = 0; rr < 3; rr++)
#pragma unroll
            for (int e = 0; e < 4; e++) { cm1[rr][e] = cc[rr][e]; cc[rr][e] = cn[rr][e]; }
    }
}

extern "C" void kernel_launch(void* const* d_in, const int* in_sizes, int n_in,
                              void* d_out, int out_size, void* d_ws, size_t ws_size,
                              hipStream_t stream)
{
    (void)in_sizes; (void)n_in; (void)ws_size; (void)out_size;
    const float* x      = (const float*)d_in[0];
    const int*   ridx   = (const int*)d_in[1];
    const float* n1g    = (const float*)d_in[4];
    const float* n1b    = (const float*)d_in[5];
    const float* in_w   = (const float*)d_in[6];
    const float* conv_w = (const float*)d_in[7];
    const float* conv_b = (const float*)d_in[8];
    const float* xp_w   = (const float*)d_in[9];
    const float* dt_w   = (const float*)d_in[10];
    const float* dt_b   = (const float*)d_in[11];
    const float* A_log  = (const float*)d_in[12];
    const float* Dp     = (const float*)d_in[13];
    const float* out_w  = (const float*)d_in[14];
    const float* n2g    = (const float*)d_in[15];
    const float* n2b    = (const float*)d_in[16];
    const float* gate_w = (const float*)d_in[17];
    const float* fc1_w  = (const float*)d_in[18];
    const float* fc1_b  = (const float*)d_in[19];
    const float* pe_w   = (const float*)d_in[20];
    const float* pe_b   = (const float*)d_in[21];
    const float* fc2_w  = (const float*)d_in[22];
    const float* fc2_b  = (const float*)d_in[23];
    float* out = (float*)d_out;

    float* ws = (float*)d_ws;
    short* wb   = (short*)ws;                       // [0, 215040)
    float* regA = ws + 215040;                      // xn(bf16) -> I(f32) -> tbuf(bf16)   [2,097,152]
    float* regB = regA + 2097152;                   // hg(bf16, 8192x768) -> {x1,xn2,t2}  [9,437,184]
    float* regC = regB + 9437184;                   // ub(bf16)                           [4,718,592]
    float* regD = regC + 4718592;                   // ymix(bf16)                         [4,718,592]
    float* regE = regD + 4718592;                   // dtb(bf16)                          [4,718,592]
    float* regF = regE + 4718592;                   // PS (f32 pairs)                     [2,359,296]
    float* regG = regF + 2359296;                   // xpbc (f32)                         [196,608]
    float* smallb = regG + 196608;

    short* xn   = (short*)regA;
    float* Ibuf = regA;
    short* tbuf = (short*)regA;
    short* hg   = (short*)regB;                     // 8192*768 bf16
    float* x1   = regB + 3145728;
    short* xn2  = (short*)(regB + 4194304);
    short* t2   = (short*)(regB + 4718592);
    short* ub   = (short*)regC;
    short* ymix = (short*)regD;
    short* dtb  = (short*)regE;
    float* PS   = regF;
    float* xpbc = regG;
    float* colsum = smallb;                         // 6*384 f32
    float* gwcb   = smallb + 2304;                  // 3456 f32
    float* gbuf   = gwcb + 3456;                    // 8 f32
    int*   invb   = (int*)(gbuf + 8);               // 4096 int

    const int M6 = SBN * LLEN;   // 24576
    const int M2 = NB * LLEN;    // 8192

    conv_comp<<<NCBLK + 576 + GWCBLK + 16, 256, 0, stream>>>(in_w, xp_w, dt_w, out_w, fc1_w, fc2_w,
                                                             gate_w, ridx, wb, colsum, gwcb, invb);
    // LN1 on fwd rows only (rev/shf are row permutations of fwd through the linear ops)
    prep_ln1<<<M2 / 4, 256, 0, stream>>>(x, n1g, n1b, xn);
    // fused in_proj: [h | gate] N=768, bf16 out, M=8192
    gemm_w<5><<<dim3(M2 / 64, 6), 256, 0, stream>>>(xn, CCH, wb + OFF_IN, CCH, 768, nullptr, nullptr, 0, nullptr, hg, 768, nullptr, CCH);
    // depthwise conv with per-direction row gather
    dwconv_silu_v3<<<768, 192, 0, stream>>>(hg, ridx, conv_w, conv_b, ub);
    // merged dt(softplus, bf16) + B/C(f32) projection: N=392
    gemm_w<7><<<dim3(M6 / 64, 4), 256, 0, stream>>>(ub, DI, wb + OFF_DTC, DI, 392, dt_b, nullptr, 0, nullptr, dtb, DI, xpbc, DI);
    // selective scan (3 kernels; launch boundaries are the grid barriers)
    scan_phaseA2<<<SBN * NCHUNK, DI, 0, stream>>>(dtb, xpbc, ub, A_log, PS);
    scan_phaseB2<<<36, 256, 0, stream>>>(PS, Ibuf);
    scan_phaseC3<<<SBN * NCHUNK, DI, 0, stream>>>(dtb, xpbc, ub, hg, ridx, A_log, Dp, Ibuf, ymix, colsum);
    // gating weights via precomputed gwc (tiny)
    gate3<<<1, 384, 0, stream>>>(colsum, gwcb, gbuf);
    // fused combine + out_proj + residual + LN2
    combine_outproj_ln2<<<M2 / 64, 256, 0, stream>>>(ymix, x, gbuf, invb, wb + OFF_OUT, n2g, n2b, x1, xn2);
    // MixFFN
    gemm_w<6><<<dim3(M2 / 64, 4), 256, 0, stream>>>(xn2, CCH, wb + OFF_FC1, CCH, FCH, fc1_b, nullptr, 0, nullptr, tbuf, FCH, nullptr, CCH);
    peconv_gelu_v2<<<256, 256, 0, stream>>>(tbuf, pe_w, pe_b, t2);
    gemm_w<3><<<dim3(M2 / 64, 1), 256, 0, stream>>>(t2, FCH, wb + OFF_FC2, FCH, CCH, fc2_b, x1, CCH, out, nullptr, CCH, nullptr, FCH);
}

// Round 9
// 173.611 us; speedup vs baseline: 1.2538x; 1.0401x over previous
//
#include <hip/hip_runtime.h>
#include <math.h>

#define LLEN 4096
#define CCH 128
#define DI 384
#define NST 4
#define SBN 6        // 3 directions x B=2
#define NB 2
#define FCH 512
#define NCHUNK 128
#define TSTEP 32

typedef short bf16x8 __attribute__((ext_vector_type(8)));
typedef short bf16x4 __attribute__((ext_vector_type(4)));
typedef float f32x4 __attribute__((ext_vector_type(4)));
typedef float f32x8 __attribute__((ext_vector_type(8)));

__device__ __forceinline__ float wave_sum(float v) {
#pragma unroll
    for (int o = 32; o > 0; o >>= 1) v += __shfl_xor(v, o);
    return v;
}

__device__ __forceinline__ short f2bf(float f) {
    unsigned int u = __float_as_uint(f);
    unsigned int r = (u + 0x7fffu + ((u >> 16) & 1u)) >> 16;
    return (short)r;
}
__device__ __forceinline__ float bf2f(short s) {
    return __uint_as_float(((unsigned int)(unsigned short)s) << 16);
}

// ---------------- weight bf16 pool offsets (elements) ----------------
#define OFF_IN  0         // in_w                 768x128
#define OFF_DTC 98304     // composed dt_w@xp_w[:128]  384x384 (rows 0..383)
#define OFF_BC  245760    //   + xp_w rows 128..135 as rows 384..391 (same ld=384)
#define OFF_OUT 248832    // out_w                128x384
#define OFF_FC1 297984    // fc1_w                512x128
#define OFF_FC2 363520    // fc2_w                128x512
#define OFF_END 429056
#define NCONV   281600    // convertible elements (everything except DTC region)
#define NCBLK   1100      // ceil(281600/256)
#define GWCBLK  14        // ceil(3456/256)
#define LN1OFF  (NCBLK + 576 + GWCBLK + 16)   // 1706
#define LN1BLK  2048                          // 8192 rows / 4

// mega-prep: conversions + dt_w@xp_w composition + gwc + inverse perm + colsum zero + LN1
__global__ __launch_bounds__(256) void conv_comp(const float* __restrict__ in_w,
                                                 const float* __restrict__ xp_w,
                                                 const float* __restrict__ dt_w,
                                                 const float* __restrict__ out_w,
                                                 const float* __restrict__ fc1_w,
                                                 const float* __restrict__ fc2_w,
                                                 const float* __restrict__ gate_w,
                                                 const int* __restrict__ ridx,
                                                 const float* __restrict__ x,
                                                 const float* __restrict__ n1g,
                                                 const float* __restrict__ n1b,
                                                 short* __restrict__ wb,
                                                 float* __restrict__ colsum,
                                                 float* __restrict__ gwc,
                                                 int* __restrict__ inv,
                                                 short* __restrict__ xn)
{
    int bid = blockIdx.x;
    if (bid < NCBLK) {
        int i = bid * 256 + threadIdx.x;
        if (i >= NCONV) return;
        int idx = (i < OFF_DTC) ? i : i + (OFF_OUT - OFF_DTC);  // skip composed region
        float v;
        if (idx < OFF_DTC)      v = in_w[idx];
        else if (idx < OFF_OUT) v = xp_w[128 * 384 + (idx - OFF_BC)];   // bc rows
        else if (idx < OFF_FC1) v = out_w[idx - OFF_OUT];
        else if (idx < OFF_FC2) v = fc1_w[idx - OFF_FC1];
        else                    v = fc2_w[idx - OFF_FC2];
        wb[idx] = f2bf(v);
    } else if (bid < NCBLK + 576) {
        if (bid == NCBLK) {
            for (int i = threadIdx.x; i < SBN * DI; i += 256) colsum[i] = 0.f;
        }
        int ji = (bid - NCBLK) * 256 + threadIdx.x;   // 0 .. 147455
        int j = ji / 384, k = ji % 384;
        float acc = 0.f;
#pragma unroll 8
        for (int n = 0; n < 128; n++)
            acc += dt_w[j * 128 + n] * xp_w[n * 384 + k];
        wb[OFF_DTC + j * 384 + k] = f2bf(acc);
    } else if (bid < NCBLK + 576 + GWCBLK) {
        // gwc[j][s][d] = sum_c gate_w[j, s*128+c] * out_w[c, d]
        int idx = (bid - NCBLK - 576) * 256 + threadIdx.x;
        if (idx >= 3456) return;
        int j = idx / 1152, rem = idx % 1152;
        int s = rem / 384, d = rem % 384;
        float acc = 0.f;
#pragma unroll 8
        for (int c = 0; c < 128; c++)
            acc += gate_w[j * 384 + s * 128 + c] * out_w[c * 384 + d];
        gwc[idx] = acc;
    } else if (bid < LN1OFF) {
        int l = (bid - NCBLK - 576 - GWCBLK) * 256 + threadIdx.x;
        if (l < LLEN) inv[ridx[l]] = l;
    } else {
        // LayerNorm over C=128, FWD rows only (perm invariance), 4 rows/block
        int r = (bid - LN1OFF) * 4 + (threadIdx.x >> 6);   // 0 .. 8191
        int lane = threadIdx.x & 63;
        const float* src = x + (size_t)r * CCH;
        float v0 = src[lane], v1 = src[lane + 64];
        float m = wave_sum(v0 + v1) * (1.f / 128.f);
        float d0 = v0 - m, d1 = v1 - m;
        float var = wave_sum(d0 * d0 + d1 * d1) * (1.f / 128.f);
        float rstd = rsqrtf(var + 1e-5f);
        short* dst = xn + (size_t)r * CCH;
        dst[lane]      = f2bf(d0 * rstd * n1g[lane]      + n1b[lane]);
        dst[lane + 64] = f2bf(d1 * rstd * n1g[lane + 64] + n1b[lane + 64]);
    }
}

// ---------------- wide MFMA GEMM (64x128 tile) ----------------
// EPI: 3=bias+residual f32   5=bf16   6=bias bf16
//      7=dtc+bc split: col<384 bias+softplus bf16 -> Cb; col 384..391 f32 -> extra
template<int EPI>
__global__ __launch_bounds__(256) void gemm_w(const short* __restrict__ A, int lda,
                                              const short* __restrict__ W, int ldw, int Ntot,
                                              const float* __restrict__ bias,
                                              const float* __restrict__ res, int ldr,
                                              float* __restrict__ C0,
                                              short* __restrict__ Cb, int ldc,
                                              float* __restrict__ extra,
                                              int Kd)
{
    __shared__ short Als[64 * 72];
    __shared__ short Wls[128 * 72];
    int tid = threadIdx.x;
    int wid = tid >> 6, lane = tid & 63;
    int wm = wid >> 1, wn = wid & 1;
    int l15 = lane & 15, l4 = lane >> 4;
    int bm = blockIdx.x * 64, bn = blockIdx.y * 128;
    int srow = tid >> 3, scol = (tid & 7) * 8;
    const bool tail = (EPI == 7) && (bn >= 384);   // only 8 of 128 cols live
    f32x4 acc[2][4] = {};
    for (int k0 = 0; k0 < Kd; k0 += 64) {
        bf16x8 av0 = *(const bf16x8*)&A[(size_t)(bm + srow) * lda + k0 + scol];
        bf16x8 av1 = *(const bf16x8*)&A[(size_t)(bm + srow + 32) * lda + k0 + scol];
        bf16x8 wv[4];
#pragma unroll
        for (int q = 0; q < 4; q++) {
            if (EPI == 7) {
                wv[q] = bf16x8{};
                if (bn + srow + 32 * q < Ntot)
                    wv[q] = *(const bf16x8*)&W[(size_t)(bn + srow + 32 * q) * ldw + k0 + scol];
            } else {
                wv[q] = *(const bf16x8*)&W[(size_t)(bn + srow + 32 * q) * ldw + k0 + scol];
            }
        }
        __syncthreads();
        *(bf16x8*)&Als[srow * 72 + scol] = av0;
        *(bf16x8*)&Als[(srow + 32) * 72 + scol] = av1;
#pragma unroll
        for (int q = 0; q < 4; q++)
            *(bf16x8*)&Wls[(srow + 32 * q) * 72 + scol] = wv[q];
        __syncthreads();
        if (!tail) {
#pragma unroll
            for (int ks = 0; ks < 2; ks++) {
                bf16x8 af[2], bw[4];
#pragma unroll
                for (int f = 0; f < 2; f++)
                    af[f] = *(const bf16x8*)&Als[(wm * 32 + f * 16 + l15) * 72 + ks * 32 + l4 * 8];
#pragma unroll
                for (int j = 0; j < 4; j++)
                    bw[j] = *(const bf16x8*)&Wls[(wn * 64 + j * 16 + l15) * 72 + ks * 32 + l4 * 8];
#pragma unroll
                for (int i = 0; i < 2; i++)
#pragma unroll
                    for (int j = 0; j < 4; j++)
                        acc[i][j] = __builtin_amdgcn_mfma_f32_16x16x32_bf16(af[i], bw[j], acc[i][j], 0, 0, 0);
            }
        } else if (wn == 0) {
            // tail block: only first 16-col fragment of wn==0 waves is live
#pragma unroll
            for (int ks = 0; ks < 2; ks++) {
                bf16x8 af[2];
#pragma unroll
                for (int f = 0; f < 2; f++)
                    af[f] = *(const bf16x8*)&Als[(wm * 32 + f * 16 + l15) * 72 + ks * 32 + l4 * 8];
                bf16x8 bw0 = *(const bf16x8*)&Wls[(l15)*72 + ks * 32 + l4 * 8];
#pragma unroll
                for (int i = 0; i < 2; i++)
                    acc[i][0] = __builtin_amdgcn_mfma_f32_16x16x32_bf16(af[i], bw0, acc[i][0], 0, 0, 0);
            }
        }
    }
#pragma unroll
    for (int i = 0; i < 2; i++) {
        int row0 = bm + wm * 32 + i * 16 + l4 * 4;
#pragma unroll
        for (int j = 0; j < 4; j++) {
            int col = bn + wn * 64 + j * 16 + l15;
            if (EPI == 7) {
                if (col < 384) {
                    float bv = bias[col];
#pragma unroll
                    for (int r = 0; r < 4; r++) {
                        float v = acc[i][j][r] + bv;
                        v = (v > 20.f) ? v : __logf(1.f + __expf(v));
                        Cb[(size_t)(row0 + r) * ldc + col] = f2bf(v);
                    }
                } else if (col < 392) {
#pragma unroll
                    for (int r = 0; r < 4; r++)
                        extra[(size_t)(row0 + r) * 8 + (col - 384)] = acc[i][j][r];
                }
            } else {
                float bv = (EPI == 3 || EPI == 6) ? bias[col] : 0.f;
#pragma unroll
                for (int r = 0; r < 4; r++) {
                    float v = acc[i][j][r] + bv;
                    if (EPI == 3) v += res[(size_t)(row0 + r) * ldr + col];
                    if (EPI == 5 || EPI == 6)
                        Cb[(size_t)(row0 + r) * ldc + col] = f2bf(v);
                    else
                        C0[(size_t)(row0 + r) * ldc + col] = v;
                }
            }
        }
    }
}

// ---------------- depthwise causal conv K=4 + bias + SiLU over permuted views of hg_fwd ----------------
__global__ __launch_bounds__(192) void dwconv_silu_v3(const short* __restrict__ hg,
                                                      const int* __restrict__ ridx,
                                                      const float* __restrict__ cw,
                                                      const float* __restrict__ cb,
                                                      short* __restrict__ ub)
{
    int t = threadIdx.x;
    int c = t % 48, rs = t / 48;
    int blk = blockIdx.x;            // 768 blocks: 6 sb x 128
    int sb = blk >> 7;
    int s = sb >> 1, bb = sb & 1;
    int l0 = ((blk & 127) << 5) + rs * 8;
    int d0 = c * 8;
    float w0[8], w1[8], w2[8], w3[8], bs[8];
#pragma unroll
    for (int e = 0; e < 8; e++) {
        int d = d0 + e;
        bs[e] = cb[d];
        w0[e] = cw[d * 4 + 0]; w1[e] = cw[d * 4 + 1];
        w2[e] = cw[d * 4 + 2]; w3[e] = cw[d * 4 + 3];
    }
    float r0[8], r1[8], r2[8];
#pragma unroll
    for (int e = 0; e < 8; e++) { r0[e] = 0.f; r1[e] = 0.f; r2[e] = 0.f; }
    if (l0 - 3 >= 0) {
        int j = l0 - 3;
        int sl = (s == 0) ? j : (s == 1 ? LLEN - 1 - j : ridx[j]);
        bf16x8 v = *(const bf16x8*)&hg[(size_t)(bb * LLEN + sl) * 768 + d0];
#pragma unroll
        for (int e = 0; e < 8; e++) r0[e] = bf2f(v[e]);
    }
    if (l0 - 2 >= 0) {
        int j = l0 - 2;
        int sl = (s == 0) ? j : (s == 1 ? LLEN - 1 - j : ridx[j]);
        bf16x8 v = *(const bf16x8*)&hg[(size_t)(bb * LLEN + sl) * 768 + d0];
#pragma unroll
        for (int e = 0; e < 8; e++) r1[e] = bf2f(v[e]);
    }
    if (l0 - 1 >= 0) {
        int j = l0 - 1;
        int sl = (s == 0) ? j : (s == 1 ? LLEN - 1 - j : ridx[j]);
        bf16x8 v = *(const bf16x8*)&hg[(size_t)(bb * LLEN + sl) * 768 + d0];
#pragma unroll
        for (int e = 0; e < 8; e++) r2[e] = bf2f(v[e]);
    }
#pragma unroll
    for (int i = 0; i < 8; i++) {
        int j = l0 + i;
        int sl = (s == 0) ? j : (s == 1 ? LLEN - 1 - j : ridx[j]);
        bf16x8 v = *(const bf16x8*)&hg[(size_t)(bb * LLEN + sl) * 768 + d0];
        float r3[8];
#pragma unroll
        for (int e = 0; e < 8; e++) r3[e] = bf2f(v[e]);
        bf16x8 ov;
#pragma unroll
        for (int e = 0; e < 8; e++) {
            float a = bs[e] + w0[e] * r0[e] + w1[e] * r1[e] + w2[e] * r2[e] + w3[e] * r3[e];
            ov[e] = f2bf(a * __builtin_amdgcn_rcpf(1.f + __expf(-a)));
        }
        *(bf16x8*)&ub[(size_t)(sb * LLEN + j) * DI + d0] = ov;
#pragma unroll
        for (int e = 0; e < 8; e++) { r0[e] = r1[e]; r1[e] = r2[e]; r2[e] = r3[e]; }
    }
}

// ---------------- scan phase A: per-chunk zero-init scan, LDS-staged ----------------
__global__ __launch_bounds__(DI) void scan_phaseA2(const short* __restrict__ dtb,
                                                   const float* __restrict__ bc,
                                                   const short* __restrict__ ub,
                                                   const float* __restrict__ A_log,
                                                   float* __restrict__ PS)
{
    __shared__ short ds_dt[TSTEP * DI];
    __shared__ short ds_u[TSTEP * DI];
    __shared__ float ds_bc[TSTEP * 8];
    int tid = threadIdx.x;
    int bid = blockIdx.x;
    int sb = bid / NCHUNK, chunk = bid % NCHUNK;
    int base = sb * LLEN + chunk * TSTEP;
    {
        int rr = tid / 48, cc = (tid % 48) * 8;
#pragma unroll
        for (int p = 0; p < 4; p++) {
            int row = p * 8 + rr;
            *(bf16x8*)&ds_dt[row * DI + cc] = *(const bf16x8*)&dtb[(size_t)(base + row) * DI + cc];
            *(bf16x8*)&ds_u[row * DI + cc]  = *(const bf16x8*)&ub[(size_t)(base + row) * DI + cc];
        }
        if (tid < TSTEP * 8) ds_bc[tid] = bc[(size_t)base * 8 + tid];
    }
    int d = tid;
    f32x4 al = *(const f32x4*)&A_log[d * 4];
    float a[NST];
#pragma unroll
    for (int n = 0; n < NST; n++) a[n] = -__expf(al[n]);
    __syncthreads();
    float s[NST] = {0.f, 0.f, 0.f, 0.f}, p[NST] = {1.f, 1.f, 1.f, 1.f};
    for (int t = 0; t < TSTEP; t++) {
        float dtv = bf2f(ds_dt[t * DI + d]);
        float dtu = dtv * bf2f(ds_u[t * DI + d]);
#pragma unroll
        for (int n = 0; n < NST; n++) {
            float dA = __expf(dtv * a[n]);
            s[n] = dA * s[n] + dtu * ds_bc[t * 8 + n];
            p[n] *= dA;
        }
    }
    f32x8 v;
#pragma unroll
    for (int n = 0; n < NST; n++) { v[2 * n] = p[n]; v[2 * n + 1] = s[n]; }
    *(f32x8*)&PS[(size_t)(sb * NCHUNK + chunk) * 3072 + d * 8] = v;
}

// ---------------- scan phase B: cross-chunk prefix ----------------
__global__ __launch_bounds__(256) void scan_phaseB2(const float* __restrict__ PS,
                                                    float* __restrict__ I)
{
    int gid = blockIdx.x * 256 + threadIdx.x;
    if (gid >= SBN * 1536) return;
    int sb = gid / 1536, dn = gid % 1536;
    const float* ps = PS + (size_t)sb * NCHUNK * 3072 + dn * 2;
    float* Ip = I + (size_t)sb * NCHUNK * 1536 + dn;
    float st = 0.f;
    for (int c = 0; c < NCHUNK; c += 8) {
        float2 v[8];
#pragma unroll
        for (int q = 0; q < 8; q++) v[q] = *(const float2*)&ps[(size_t)(c + q) * 3072];
#pragma unroll
        for (int q = 0; q < 8; q++) { Ip[(size_t)(c + q) * 1536] = st; st = v[q].x * st + v[q].y; }
    }
}

// ---------------- scan phase C: re-scan + gate + ymix + per-column sums ----------------
__global__ __launch_bounds__(DI) void scan_phaseC3(const short* __restrict__ dtb,
                                                   const float* __restrict__ bc,
                                                   const short* __restrict__ ub,
                                                   const short* __restrict__ hg,
                                                   const int* __restrict__ ridx,
                                                   const float* __restrict__ A_log,
                                                   const float* __restrict__ Dp,
                                                   const float* __restrict__ I,
                                                   short* __restrict__ ymix,
                                                   float* __restrict__ colsum)
{
    __shared__ short ds_dt[TSTEP * DI];
    __shared__ short ds_u[TSTEP * DI];
    __shared__ float ds_bc[TSTEP * 8];
    __shared__ int ds_src[TSTEP];
    int tid = threadIdx.x;
    int bid = blockIdx.x;
    int sb = bid / NCHUNK, chunk = bid % NCHUNK;
    int s2 = sb >> 1, bb = sb & 1;
    int base = sb * LLEN + chunk * TSTEP;
    {
        int rr = tid / 48, cc = (tid % 48) * 8;
#pragma unroll
        for (int p = 0; p < 4; p++) {
            int row = p * 8 + rr;
            *(bf16x8*)&ds_dt[row * DI + cc] = *(const bf16x8*)&dtb[(size_t)(base + row) * DI + cc];
            *(bf16x8*)&ds_u[row * DI + cc]  = *(const bf16x8*)&ub[(size_t)(base + row) * DI + cc];
        }
        if (tid < TSTEP * 8) ds_bc[tid] = bc[(size_t)base * 8 + tid];
        if (tid < TSTEP) {
            int l = chunk * TSTEP + tid;
            int sl = (s2 == 0) ? l : (s2 == 1 ? LLEN - 1 - l : ridx[l]);
            ds_src[tid] = bb * LLEN + sl;
        }
    }
    int d = tid;
    f32x4 al = *(const f32x4*)&A_log[d * 4];
    float a[NST];
#pragma unroll
    for (int n = 0; n < NST; n++) a[n] = -__expf(al[n]);
    __syncthreads();
    float s[NST];
    {
        f32x4 si = *(const f32x4*)&I[(size_t)(sb * NCHUNK + chunk) * 1536 + d * 4];
#pragma unroll
        for (int n = 0; n < NST; n++) s[n] = si[n];
    }
    float Dv = Dp[d];
    float csum = 0.f;
    for (int t = 0; t < TSTEP; t++) {
        float dtv = bf2f(ds_dt[t * DI + d]);
        float uv = bf2f(ds_u[t * DI + d]);
        float dtu = dtv * uv;
        float y = 0.f;
#pragma unroll
        for (int n = 0; n < NST; n++) {
            float dA = __expf(dtv * a[n]);
            s[n] = dA * s[n] + dtu * ds_bc[t * 8 + n];
            y += s[n] * ds_bc[t * 8 + 4 + n];
        }
        float gt = bf2f(hg[(size_t)ds_src[t] * 768 + 384 + d]);
        float sg = gt * __builtin_amdgcn_rcpf(1.f + __expf(-gt));
        float val = (y + uv * Dv) * sg;
        ymix[(size_t)(base + t) * DI + d] = f2bf(val);
        csum += val;
    }
    atomicAdd(&colsum[sb * DI + d], csum);
}

// ---------------- fused: gate softmax (per-block, redundant) + direction-combine
//                  + out_proj GEMM + residual + LN2 ----------------
__global__ __launch_bounds__(256) void combine_outproj_ln2(const short* __restrict__ ymix,
                                                           const float* __restrict__ x,
                                                           const float* __restrict__ colsum,
                                                           const float* __restrict__ gwc,
                                                           const int* __restrict__ inv,
                                                           const short* __restrict__ Wout,
                                                           const float* __restrict__ n2g,
                                                           const float* __restrict__ n2b,
                                                           float* __restrict__ x1,
                                                           short* __restrict__ xn2)
{
    __shared__ short Als[64 * 72];
    __shared__ short Wls[128 * 72];
    __shared__ float xs[64][132];
    __shared__ int ssrc[192];
    __shared__ float msh[64], rsh[64];
    __shared__ float part[4][3];
    __shared__ float gsh[3];
    int tid = threadIdx.x;
    int bm = blockIdx.x * 64;          // global row over 8192
    int bb = bm >> 12;
    if (tid < 64) {
        int l = (bm & 4095) + tid;
        ssrc[tid * 3 + 0] = bb * LLEN + l;
        ssrc[tid * 3 + 1] = (2 + bb) * LLEN + (LLEN - 1 - l);
        ssrc[tid * 3 + 2] = (4 + bb) * LLEN + inv[l];
    }
    int wid = tid >> 6, lane = tid & 63;
    // gate logits (redundant per block; L2-hot inputs)
    {
        float a0 = 0.f, a1 = 0.f, a2 = 0.f;
        for (int i = tid; i < 1152; i += 256) {
            int s = i / 384, d = i % 384;
            float cv = colsum[(s * 2 + bb) * 384 + d];
            a0 += cv * gwc[i];
            a1 += cv * gwc[1152 + i];
            a2 += cv * gwc[2304 + i];
        }
        a0 = wave_sum(a0); a1 = wave_sum(a1); a2 = wave_sum(a2);
        if (lane == 0) { part[wid][0] = a0; part[wid][1] = a1; part[wid][2] = a2; }
    }
    __syncthreads();
    if (tid == 0) {
        float l0 = 0.f, l1 = 0.f, l2 = 0.f;
#pragma unroll
        for (int w = 0; w < 4; w++) { l0 += part[w][0]; l1 += part[w][1]; l2 += part[w][2]; }
        l0 *= (1.f / 4096.f); l1 *= (1.f / 4096.f); l2 *= (1.f / 4096.f);
        float mx = fmaxf(l0, fmaxf(l1, l2));
        float e0 = __expf(l0 - mx), e1 = __expf(l1 - mx), e2 = __expf(l2 - mx);
        float iv = __builtin_amdgcn_rcpf(e0 + e1 + e2);
        gsh[0] = e0 * iv; gsh[1] = e1 * iv; gsh[2] = e2 * iv;
    }
    __syncthreads();
    float g0 = gsh[0], g1 = gsh[1], g2 = gsh[2];
    int wm = wid >> 1, wn = wid & 1;
    int l15 = lane & 15, l4 = lane >> 4;
    int srow = tid >> 3, scol = (tid & 7) * 8;
    f32x4 acc[2][4] = {};
    for (int k0 = 0; k0 < DI; k0 += 64) {
        bf16x8 cmb[2];
#pragma unroll
        for (int hh = 0; hh < 2; hh++) {
            int r = srow + 32 * hh;
            bf16x8 vf = *(const bf16x8*)&ymix[(size_t)ssrc[r * 3 + 0] * DI + k0 + scol];
            bf16x8 vr = *(const bf16x8*)&ymix[(size_t)ssrc[r * 3 + 1] * DI + k0 + scol];
            bf16x8 vs = *(const bf16x8*)&ymix[(size_t)ssrc[r * 3 + 2] * DI + k0 + scol];
#pragma unroll
            for (int e = 0; e < 8; e++)
                cmb[hh][e] = f2bf(g0 * bf2f(vf[e]) + g1 * bf2f(vr[e]) + g2 * bf2f(vs[e]));
        }
        bf16x8 wv[4];
#pragma unroll
        for (int q = 0; q < 4; q++)
            wv[q] = *(const bf16x8*)&Wout[(size_t)(srow + 32 * q) * DI + k0 + scol];
        __syncthreads();
        *(bf16x8*)&Als[srow * 72 + scol] = cmb[0];
        *(bf16x8*)&Als[(srow + 32) * 72 + scol] = cmb[1];
#pragma unroll
        for (int q = 0; q < 4; q++)
            *(bf16x8*)&Wls[(srow + 32 * q) * 72 + scol] = wv[q];
        __syncthreads();
#pragma unroll
        for (int ks = 0; ks < 2; ks++) {
            bf16x8 af[2], bw[4];
#pragma unroll
            for (int f = 0; f < 2; f++)
                af[f] = *(const bf16x8*)&Als[(wm * 32 + f * 16 + l15) * 72 + ks * 32 + l4 * 8];
#pragma unroll
            for (int j = 0; j < 4; j++)
                bw[j] = *(const bf16x8*)&Wls[(wn * 64 + j * 16 + l15) * 72 + ks * 32 + l4 * 8];
#pragma unroll
            for (int i = 0; i < 2; i++)
#pragma unroll
                for (int j = 0; j < 4; j++)
                    acc[i][j] = __builtin_amdgcn_mfma_f32_16x16x32_bf16(af[i], bw[j], acc[i][j], 0, 0, 0);
        }
    }
    // residual add into LDS
#pragma unroll
    for (int i = 0; i < 2; i++) {
        int rowl = wm * 32 + i * 16 + l4 * 4;
#pragma unroll
        for (int j = 0; j < 4; j++) {
            int col = wn * 64 + j * 16 + l15;
#pragma unroll
            for (int r = 0; r < 4; r++)
                xs[rowl + r][col] = acc[i][j][r] + x[(size_t)(bm + rowl + r) * CCH + col];
        }
    }
    __syncthreads();
    // row LN stats: 4 threads per row
    {
        int row = tid >> 2, q = tid & 3;
        float sum = 0.f, sq = 0.f;
#pragma unroll
        for (int c = q * 32; c < q * 32 + 32; c++) { float v = xs[row][c]; sum += v; sq += v * v; }
        sum += __shfl_xor(sum, 1); sq += __shfl_xor(sq, 1);
        sum += __shfl_xor(sum, 2); sq += __shfl_xor(sq, 2);
        if (q == 0) {
            float m = sum * (1.f / 128.f);
            float var = sq * (1.f / 128.f) - m * m;
            msh[row] = m;
            rsh[row] = rsqrtf(fmaxf(var, 0.f) + 1e-5f);
        }
    }
    __syncthreads();
    {
        int col = tid & 127;
        float gg = n2g[col], b2 = n2b[col];
#pragma unroll
        for (int e = 0; e < 32; e++) {
            int row = e * 2 + (tid >> 7);
            float v = xs[row][col];
            x1[(size_t)(bm + row) * CCH + col] = v;
            xn2[(size_t)(bm + row) * CCH + col] = f2bf((v - msh[row]) * rsh[row] * gg + b2);
        }
    }
}

// ---------------- 3x3 depthwise conv + exact GeLU: sliding-window vectorized ----------------
__global__ __launch_bounds__(256) void peconv_gelu_v2(const short* __restrict__ t,
                                                      const float* __restrict__ pw,
                                                      const float* __restrict__ pb,
                                                      short* __restrict__ t2)
{
    int tid = threadIdx.x;
    int fc = tid & 127;
    int wsr = tid >> 7;
    int blk = blockIdx.x;
    int whalf = blk & 1, h = (blk >> 1) & 63, bb = blk >> 7;
    int w0 = whalf * 32 + wsr * 16;
    int f0 = fc * 4;
    float wt[9][4], bias4[4];
#pragma unroll
    for (int e = 0; e < 4; e++) {
        bias4[e] = pb[f0 + e];
#pragma unroll
        for (int k = 0; k < 9; k++) wt[k][e] = pw[(f0 + e) * 9 + k];
    }
    size_t base = (size_t)bb * 4096 * FCH;
    float cm1[3][4], cc[3][4], cn[3][4];
#pragma unroll
    for (int rr = 0; rr < 3; rr++)
#pragma unroll
        for (int e = 0; e < 4; e++) { cm1[rr][e] = 0.f; cc[rr][e] = 0.f; }
#pragma unroll
    for (int rr = 0; rr < 3; rr++) {
        int hh = h + rr - 1;
        if (hh >= 0 && hh < 64) {
            if (w0 - 1 >= 0) {
                bf16x4 v = *(const bf16x4*)&t[base + ((size_t)hh * 64 + (w0 - 1)) * FCH + f0];
#pragma unroll
                for (int e = 0; e < 4; e++) cm1[rr][e] = bf2f(v[e]);
            }
            bf16x4 v = *(const bf16x4*)&t[base + ((size_t)hh * 64 + w0) * FCH + f0];
#pragma unroll
            for (int e = 0; e < 4; e++) cc[rr][e] = bf2f(v[e]);
        }
    }
#pragma unroll
    for (int i = 0; i < 16; i++) {
        int w = w0 + i;
#pragma unroll
        for (int rr = 0; rr < 3; rr++) {
#pragma unroll
            for (int e = 0; e < 4; e++) cn[rr][e] = 0.f;
            int hh = h + rr - 1;
            if (hh >= 0 && hh < 64 && w + 1 < 64) {
                bf16x4 v = *(const bf16x4*)&t[base + ((size_t)hh * 64 + (w + 1)) * FCH + f0];
#pragma unroll
                for (int e = 0; e < 4; e++) cn[rr][e] = bf2f(v[e]);
            }
        }
        bf16x4 ov;
#pragma unroll
        for (int e = 0; e < 4; e++) {
            float acc = bias4[e];
#pragma unroll
            for (int rr = 0; rr < 3; rr++) {
                acc += wt[rr * 3 + 0][e] * cm1[rr][e];
                acc += wt[rr * 3 + 1][e] * cc[rr][e];
                acc += wt[rr * 3 + 2][e] * cn[rr][e];
            }
            ov[e] = f2bf(0.5f * acc * (1.f + erff(acc * 0.70710678118654752f)));
        }
        *(bf16x4*)&t2[base + ((size_t)h * 64 + w) * FCH + f0] = ov;
#pragma unroll
        for (int rr = 0; rr < 3; rr++)
#pragma unroll
            for (int e = 0; e < 4; e++) { cm1[rr][e] = cc[rr][e]; cc[rr][e] = cn[rr][e]; }
    }
}

extern "C" void kernel_launch(void* const* d_in, const int* in_sizes, int n_in,
                              void* d_out, int out_size, void* d_ws, size_t ws_size,
                              hipStream_t stream)
{
    (void)in_sizes; (void)n_in; (void)ws_size; (void)out_size;
    const float* x      = (const float*)d_in[0];
    const int*   ridx   = (const int*)d_in[1];
    const float* n1g    = (const float*)d_in[4];
    const float* n1b    = (const float*)d_in[5];
    const float* in_w   = (const float*)d_in[6];
    const float* conv_w = (const float*)d_in[7];
    const float* conv_b = (const float*)d_in[8];
    const float* xp_w   = (const float*)d_in[9];
    const float* dt_w   = (const float*)d_in[10];
    const float* dt_b   = (const float*)d_in[11];
    const float* A_log  = (const float*)d_in[12];
    const float* Dp     = (const float*)d_in[13];
    const float* out_w  = (const float*)d_in[14];
    const float* n2g    = (const float*)d_in[15];
    const float* n2b    = (const float*)d_in[16];
    const float* gate_w = (const float*)d_in[17];
    const float* fc1_w  = (const float*)d_in[18];
    const float* fc1_b  = (const float*)d_in[19];
    const float* pe_w   = (const float*)d_in[20];
    const float* pe_b   = (const float*)d_in[21];
    const float* fc2_w  = (const float*)d_in[22];
    const float* fc2_b  = (const float*)d_in[23];
    float* out = (float*)d_out;

    float* ws = (float*)d_ws;
    short* wb   = (short*)ws;                       // [0, 215040)
    float* regA = ws + 215040;                      // xn(bf16) -> I(f32) -> tbuf(bf16)   [2,097,152]
    float* regB = regA + 2097152;                   // hg(bf16, 8192x768) -> {x1,xn2,t2}  [9,437,184]
    float* regC = regB + 9437184;                   // ub(bf16)                           [4,718,592]
    float* regD = regC + 4718592;                   // ymix(bf16)                         [4,718,592]
    float* regE = regD + 4718592;                   // dtb(bf16)                          [4,718,592]
    float* regF = regE + 4718592;                   // PS (f32 pairs)                     [2,359,296]
    float* regG = regF + 2359296;                   // xpbc (f32)                         [196,608]
    float* smallb = regG + 196608;

    short* xn   = (short*)regA;
    float* Ibuf = regA;
    short* tbuf = (short*)regA;
    short* hg   = (short*)regB;                     // 8192*768 bf16
    float* x1   = regB + 3145728;
    short* xn2  = (short*)(regB + 4194304);
    short* t2   = (short*)(regB + 4718592);
    short* ub   = (short*)regC;
    short* ymix = (short*)regD;
    short* dtb  = (short*)regE;
    float* PS   = regF;
    float* xpbc = regG;
    float* colsum = smallb;                         // 6*384 f32
    float* gwcb   = smallb + 2304;                  // 3456 f32
    float* gbuf   = gwcb + 3456;                    // 8 f32 (unused now)
    int*   invb   = (int*)(gbuf + 8);               // 4096 int
    (void)gbuf;

    const int M6 = SBN * LLEN;   // 24576
    const int M2 = NB * LLEN;    // 8192

    // mega-prep: weight convert/compose + gwc + inv + colsum zero + LN1
    conv_comp<<<LN1OFF + LN1BLK, 256, 0, stream>>>(in_w, xp_w, dt_w, out_w, fc1_w, fc2_w,
                                                   gate_w, ridx, x, n1g, n1b,
                                                   wb, colsum, gwcb, invb, xn);
    // fused in_proj: [h | gate] N=768, bf16 out, M=8192
    gemm_w<5><<<dim3(M2 / 64, 6), 256, 0, stream>>>(xn, CCH, wb + OFF_IN, CCH, 768, nullptr, nullptr, 0, nullptr, hg, 768, nullptr, CCH);
    // depthwise conv with per-direction row gather
    dwconv_silu_v3<<<768, 192, 0, stream>>>(hg, ridx, conv_w, conv_b, ub);
    // merged dt(softplus, bf16) + B/C(f32) projection: N=392 (tail block slimmed)
    gemm_w<7><<<dim3(M6 / 64, 4), 256, 0, stream>>>(ub, DI, wb + OFF_DTC, DI, 392, dt_b, nullptr, 0, nullptr, dtb, DI, xpbc, DI);
    // selective scan (3 kernels; launch boundaries are the grid barriers)
    scan_phaseA2<<<SBN * NCHUNK, DI, 0, stream>>>(dtb, xpbc, ub, A_log, PS);
    scan_phaseB2<<<36, 256, 0, stream>>>(PS, Ibuf);
    scan_phaseC3<<<SBN * NCHUNK, DI, 0, stream>>>(dtb, xpbc, ub, hg, ridx, A_log, Dp, Ibuf, ymix, colsum);
    // fused gate-softmax + combine + out_proj + residual + LN2
    combine_outproj_ln2<<<M2 / 64, 256, 0, stream>>>(ymix, x, colsum, gwcb, invb, wb + OFF_OUT, n2g, n2b, x1, xn2);
    // MixFFN
    gemm_w<6><<<dim3(M2 / 64, 4), 256, 0, stream>>>(xn2, CCH, wb + OFF_FC1, CCH, FCH, fc1_b, nullptr, 0, nullptr, tbuf, FCH, nullptr, CCH);
    peconv_gelu_v2<<<256, 256, 0, stream>>>(tbuf, pe_w, pe_b, t2);
    gemm_w<3><<<dim3(M2 / 64, 1), 256, 0, stream>>>(t2, FCH, wb + OFF_FC2, FCH, CCH, fc2_b, x1, CCH, out, nullptr, CCH, nullptr, FCH);
}